// Round 25
// baseline (931.977 us; speedup 1.0000x reference)
//
#include <hip/hip_runtime.h>
#include <hip/hip_bf16.h>
#include <math.h>

#define NN     8000
#define MPAD   8064    /* NN padded to 128 */
#define BATCH  4
#define SEQ    2000
#define DTR    64
#define NHTR   4
#define DHD    16
#define FFD    2048
#define TOUTD  16
#define HIDD   512
#define NHEADS 6
#define HCD    512
#define GIND   514
#define GOUT   3072
#define GOUT2  6144    /* combined xl|xr row stride */
#define NEDGE  32000
#define ELOOP  40000   /* NEDGE + NN */

#define K1     576     /* GIND padded to 64-multiple */
#define K2     1152    /* abf row stride */

#define KSPLIT 20
#define KCH    100     /* SEQ / KSPLIT */

#define CDIV(a,b) (((a)+(b)-1)/(b))

using bf16x8 = __attribute__((__ext_vector_type__(8))) __bf16;
using f32x4  = __attribute__((__ext_vector_type__(4))) float;

__device__ __forceinline__ float selu_f(float x){
  const float a = 1.6732632423543772848f;
  const float s = 1.0507009873554805f;
  return x > 0.f ? s * x : s * a * (__expf(x) - 1.f);
}

__device__ __forceinline__ unsigned short f2bf_rn(float x){
  unsigned u = __float_as_uint(x);
  unsigned r = (u + 0x7fffu + ((u >> 16) & 1u)) >> 16;
  return (unsigned short)r;
}
__device__ __forceinline__ float bf2f(unsigned short h){
  return __uint_as_float((unsigned)h << 16);
}

// ---------------------------------------------------------------------------
// Generic C[M,N] = act(A[M,K] @ W[N,K]^T + bias). fp32, 64x64 tile, BK=16.
// (out_proj, tout, lin)
// ---------------------------------------------------------------------------
template<int ACT>  // 0=none 1=relu 2=selu
__global__ __launch_bounds__(256) void k_gemm(const float* __restrict__ A,
    const float* __restrict__ W, const float* __restrict__ bias,
    float* __restrict__ C, int M, int N, int K)
{
  __shared__ float As[16][68];
  __shared__ float Ws[16][68];
  const int tid = threadIdx.x;
  const int bm = blockIdx.y * 64, bn = blockIdx.x * 64;
  const int tx = tid & 15, ty = tid >> 4;
  float acc[4][4] = {};
  for (int k0 = 0; k0 < K; k0 += 16){
    #pragma unroll
    for (int i = 0; i < 4; ++i){
      int el = tid + (i << 8);
      int kk = el & 15, r = el >> 4;
      int gk = k0 + kk;
      int gm = bm + r;
      As[kk][r] = (gm < M && gk < K) ? A[(size_t)gm * K + gk] : 0.f;
      int gn = bn + r;
      Ws[kk][r] = (gn < N && gk < K) ? W[(size_t)gn * K + gk] : 0.f;
    }
    __syncthreads();
    #pragma unroll
    for (int kk = 0; kk < 16; ++kk){
      float av[4], wv[4];
      #pragma unroll
      for (int i = 0; i < 4; ++i) av[i] = As[kk][ty*4+i];
      #pragma unroll
      for (int j = 0; j < 4; ++j) wv[j] = Ws[kk][tx*4+j];
      #pragma unroll
      for (int i = 0; i < 4; ++i)
        #pragma unroll
        for (int j = 0; j < 4; ++j) acc[i][j] = fmaf(av[i], wv[j], acc[i][j]);
    }
    __syncthreads();
  }
  #pragma unroll
  for (int i = 0; i < 4; ++i){
    int gm = bm + ty*4 + i;
    if (gm >= M) continue;
    #pragma unroll
    for (int j = 0; j < 4; ++j){
      int gn = bn + tx*4 + j;
      if (gn >= N) continue;
      float v = acc[i][j] + bias[gn];
      if (ACT == 1) v = fmaxf(v, 0.f);
      if (ACT == 2) v = selu_f(v);
      C[(size_t)gm * N + gn] = v;
    }
  }
}

// ---------------------------------------------------------------------------
// fused: out = LN(x + (bias + sum_z part[z])) * g + b   (ff2 tail + addln)
// ---------------------------------------------------------------------------
__global__ __launch_bounds__(256) void k_addln4(const float* __restrict__ x,
    const float* __restrict__ part, const float* __restrict__ bias,
    const float* __restrict__ g, const float* __restrict__ b,
    float* __restrict__ out)
{
  int row = blockIdx.x * 4 + (threadIdx.x >> 6);
  int lane = threadIdx.x & 63;
  if (row >= NN) return;
  float y = bias[lane];
  #pragma unroll
  for (int z = 0; z < 4; ++z) y += part[(size_t)z*NN*DTR + (size_t)row*64 + lane];
  float v = x[(size_t)row*64 + lane] + y;
  float s1 = v, s2 = v * v;
  #pragma unroll
  for (int o = 32; o; o >>= 1){ s1 += __shfl_xor(s1, o); s2 += __shfl_xor(s2, o); }
  float mean = s1 * (1.f/64.f);
  float var  = s2 * (1.f/64.f) - mean * mean;
  float r = rsqrtf(var + 1e-5f);
  out[(size_t)row*64 + lane] = (v - mean) * r * g[lane] + b[lane];
}

// ---------------------------------------------------------------------------
// coord tail: coord[n] = c1row . w2 + b2; refresh abf coord cols (0,1).
// ---------------------------------------------------------------------------
__global__ __launch_bounds__(256) void k_coord2(const float* __restrict__ c1,
    const float* __restrict__ w2, const float* __restrict__ b2,
    float* __restrict__ out, short* __restrict__ abf)
{
  int n = blockIdx.x, t = threadIdx.x;
  float v = c1[(size_t)n*256 + t];
  float d0 = v * w2[t], d1 = v * w2[256 + t];
  #pragma unroll
  for (int o = 32; o; o >>= 1){ d0 += __shfl_xor(d0, o); d1 += __shfl_xor(d1, o); }
  __shared__ float red[8];
  int wv = t >> 6;
  if ((t & 63) == 0){ red[wv] = d0; red[4 + wv] = d1; }
  __syncthreads();
  if (t < 2){
    float c = (t == 0 ? red[0]+red[1]+red[2]+red[3] + b2[0]
                      : red[4]+red[5]+red[6]+red[7] + b2[1]);
    out[(size_t)n*2 + t] = c;
    abf[(size_t)n*K2 + t] = (short)f2bf_rn(c);
  }
}

// ---------------------------------------------------------------------------
// weight fp32 [3072][514] -> single bf16 (RN) [3072][K1]
// ---------------------------------------------------------------------------
__global__ void k_cvt_w(const float* __restrict__ W, short* __restrict__ Wbf)
{
  int i = blockIdx.x * blockDim.x + threadIdx.x;
  if (i >= GOUT * K1) return;
  int n = i / K1, k = i - K1 * n;
  float v = (k < GIND) ? W[(size_t)n * GIND + k] : 0.f;
  Wbf[i] = (short)f2bf_rn(v);
}

// coord1_w fp32 [256][512] -> bf16 [256][K1] (cols 2..513; 0,1 & 514.. zero)
__global__ void k_cvt_wc(const float* __restrict__ W, short* __restrict__ Wbf)
{
  int i = blockIdx.x * blockDim.x + threadIdx.x;
  if (i >= 256 * K1) return;
  int n = i / K1, k = i - K1 * n;
  float v = (k >= 2 && k < GIND) ? W[(size_t)n * HIDD + (k - 2)] : 0.f;
  Wbf[i] = (short)f2bf_rn(v);
}

// ff1_w fp32 [2048][64] -> bf16
__global__ void k_cvt_w1(const float* __restrict__ W, short* __restrict__ Wbf)
{
  int i = blockIdx.x * blockDim.x + threadIdx.x;
  if (i >= FFD * 64) return;
  Wbf[i] = (short)f2bf_rn(W[i]);
}

// ff2_w fp32 [64][2048] -> bf16 [128][2048] (rows 64..127 zero)
__global__ void k_cvt_w2(const float* __restrict__ W, short* __restrict__ Wbf)
{
  int i = blockIdx.x * blockDim.x + threadIdx.x;
  if (i >= 128 * FFD) return;
  int n = i / FFD;
  Wbf[i] = (short)f2bf_rn(n < 64 ? W[i] : 0.f);
}

// A = [coord | hidden] fp32 -> bf16 (RN) [MPAD][K2] (cols 0..K1-1 used).
__global__ void k_cvt_a(const float* __restrict__ coord,
                        const float* __restrict__ hidden,
                        short* __restrict__ Abf)
{
  int i = blockIdx.x * blockDim.x + threadIdx.x;
  if (i >= MPAD * K1) return;
  int n = i / K1, k = i - K1 * n;
  float v = 0.f;
  if (n < NN && k < GIND)
    v = (k < 2) ? coord[(size_t)n*2 + k] : hidden[(size_t)n*HIDD + k - 2];
  Abf[(size_t)n * K2 + k] = (short)f2bf_rn(v);
}

// ---------------------------------------------------------------------------
// Fused embed∘in_proj weight precompute (run once).
// ---------------------------------------------------------------------------
__global__ void k_wfuse(const float* __restrict__ ipw, const float* __restrict__ ipb,
                        const float* __restrict__ ew, const float* __restrict__ eb,
                        float* __restrict__ Wp, float* __restrict__ bp)
{
  int c = blockIdx.x * blockDim.x + threadIdx.x;
  if (c >= 192) return;
  float w4[4] = {0.f, 0.f, 0.f, 0.f};
  float bb = 0.f;
  for (int d = 0; d < 64; ++d){
    float wq = ipw[c*64 + d];
    #pragma unroll
    for (int j = 0; j < 4; ++j) w4[j] = fmaf(wq, ew[d*4 + j], w4[j]);
    bb = fmaf(wq, eb[d], bb);
  }
  #pragma unroll
  for (int j = 0; j < 4; ++j) Wp[c*4 + j] = w4[j];
  bp[c] = bb + ipb[c];
}

// h[n][d] (d<64) and qkv[n][c] (c<192) directly from mesh (4-FMA dots).
__global__ __launch_bounds__(256) void k_embqkv(const float* __restrict__ mesh,
    const float* __restrict__ ew, const float* __restrict__ eb,
    const float* __restrict__ Wp, const float* __restrict__ bp,
    float* __restrict__ h, float* __restrict__ qkv)
{
  int n = blockIdx.x, t = threadIdx.x;
  float m0 = mesh[n*4+0], m1 = mesh[n*4+1], m2 = mesh[n*4+2], m3 = mesh[n*4+3];
  if (t < 64){
    const float* wr = ew + t*4;
    h[(size_t)n*64 + t] =
      fmaf(m0, wr[0], fmaf(m1, wr[1], fmaf(m2, wr[2], m3*wr[3]))) + eb[t];
  } else {
    int c = t - 64;
    const float* wr = Wp + c*4;
    qkv[(size_t)n*192 + c] =
      fmaf(m0, wr[0], fmaf(m1, wr[1], fmaf(m2, wr[2], m3*wr[3]))) + bp[c];
  }
}

// ---------------------------------------------------------------------------
// Merged GAT GEMM via MFMA bf16: C[NN][6144] = A @ [Wl|Wr]^T (+bl|br).
// 9 K-tiles of 64. LDS XOR swizzle both-sides. LDS-staged coalesced epilogue.
// 2D XCD partition: each XCD owns a 6-n-block column band (L2-resident B).
// ---------------------------------------------------------------------------
__global__ __launch_bounds__(256) void k_gat_mfma(
    const short* __restrict__ Abf, const short* __restrict__ Wbf,
    const float* __restrict__ bl, const float* __restrict__ br,
    unsigned short* __restrict__ Cb)
{
  __shared__ __align__(16) short smem[2 * 128 * 64];
  short* As = smem;
  short* Bs = smem + 128 * 64;
  const int tid  = threadIdx.x;
  int lin = blockIdx.y * 48 + blockIdx.x;          // 0..3023
  int xcd = lin & 7;                               // XCD id
  int idx = lin >> 3;                              // 0..377 within XCD
  int nb  = xcd * 6 + idx % 6;                     // fixed 6-col band per XCD
  int mb  = idx / 6;                               // sweep m
  const int bm = mb * 128, bn = nb * 128;
  const int w    = tid >> 6, lane = tid & 63;
  const int wr   = w >> 1, wc = w & 1;
  const int lrow = lane & 15;

  f32x4 acc[4][4];
  #pragma unroll
  for (int i = 0; i < 4; ++i)
    #pragma unroll
    for (int j = 0; j < 4; ++j) acc[i][j] = (f32x4){0.f, 0.f, 0.f, 0.f};

  for (int kt = 0; kt < 9; ++kt){
    int koff = kt * 64;
    __syncthreads();                 // previous tile fully consumed
    #pragma unroll
    for (int i = 0; i < 4; ++i){
      int l  = i * 256 + tid;        // 16B-chunk index 0..1023
      int r  = l >> 3, j = l & 7;
      int js = j ^ (r & 7);          // source pre-swizzle (write side)
      const short* ga = Abf + (size_t)(bm + r) * K2 + koff + js * 8;
      const short* gb = Wbf + (size_t)(bn + r) * K1 + koff + js * 8;
      short* la = As + ((i * 256 + w * 64) << 3);   // wave-uniform base
      short* lb = Bs + ((i * 256 + w * 64) << 3);
      __builtin_amdgcn_global_load_lds(
          (const __attribute__((address_space(1))) unsigned*)ga,
          (__attribute__((address_space(3))) unsigned*)la, 16, 0, 0);
      __builtin_amdgcn_global_load_lds(
          (const __attribute__((address_space(1))) unsigned*)gb,
          (__attribute__((address_space(3))) unsigned*)lb, 16, 0, 0);
    }
    __syncthreads();                 // drains vmcnt, tile ready
    #pragma unroll
    for (int ks = 0; ks < 2; ++ks){
      const int co = ((ks * 4 + (lane >> 4)) ^ (lrow & 7)) * 8;
      bf16x8 fa[4], fb[4];
      #pragma unroll
      for (int mi = 0; mi < 4; ++mi)
        fa[mi] = *(const bf16x8*)&As[(wr*64 + mi*16 + lrow) * 64 + co];
      #pragma unroll
      for (int ni = 0; ni < 4; ++ni)
        fb[ni] = *(const bf16x8*)&Bs[(wc*64 + ni*16 + lrow) * 64 + co];
      #pragma unroll
      for (int mi = 0; mi < 4; ++mi)
        #pragma unroll
        for (int ni = 0; ni < 4; ++ni)
          acc[mi][ni] = __builtin_amdgcn_mfma_f32_16x16x32_bf16(
              fa[mi], fb[ni], acc[mi][ni], 0, 0, 0);
    }
  }
  // ---- epilogue: stage 128x128 bf16 tile in LDS (reuse As|Bs = 32 KB) ----
  __syncthreads();                               // done reading As/Bs
  unsigned short* Ct = (unsigned short*)smem;
  #pragma unroll
  for (int mi = 0; mi < 4; ++mi){
    #pragma unroll
    for (int ni = 0; ni < 4; ++ni){
      int col = wc*64 + ni*16 + lrow;
      int gn  = bn + col;
      float bv = (gn < GOUT) ? bl[gn] : br[gn - GOUT];  // block-uniform branch
      #pragma unroll
      for (int j = 0; j < 4; ++j){
        int row  = wr*64 + mi*16 + (lane >> 4)*4 + j;
        int colp = col ^ (((row >> 2) & 3) << 4);       // bank-spread swizzle
        Ct[row*128 + colp] = f2bf_rn(acc[mi][ni][j] + bv);
      }
    }
  }
  __syncthreads();
  #pragma unroll
  for (int c = 0; c < 8; ++c){
    int g   = c*256 + tid;            // chunk id 0..2047 (16B chunks)
    int row = g >> 4, cc = g & 15;
    int ccp = cc ^ (((row >> 2) & 3) << 1);             // de-swizzle
    int gm  = bm + row;
    if (gm < NN){
      bf16x8 v = *(const bf16x8*)&Ct[row*128 + ccp*8];
      *(bf16x8*)&Cb[(size_t)gm * GOUT2 + bn + cc*8] = v;
    }
  }
}

// ---------------------------------------------------------------------------
// coord1 via MFMA: c1[NN][256] = selu(abf @ wcb^T + c1b). Grid (2, 63).
// ---------------------------------------------------------------------------
__global__ __launch_bounds__(256) void k_c1_mfma(
    const short* __restrict__ Abf, const short* __restrict__ Wbf,
    const float* __restrict__ c1b, float* __restrict__ C)
{
  __shared__ __align__(16) short smem[2 * 128 * 64];
  short* As = smem;
  short* Bs = smem + 128 * 64;
  const int tid  = threadIdx.x;
  const int bm = blockIdx.y * 128, bn = blockIdx.x * 128;
  const int w    = tid >> 6, lane = tid & 63;
  const int wr   = w >> 1, wc = w & 1;
  const int lrow = lane & 15;

  f32x4 acc[4][4];
  #pragma unroll
  for (int i = 0; i < 4; ++i)
    #pragma unroll
    for (int j = 0; j < 4; ++j) acc[i][j] = (f32x4){0.f, 0.f, 0.f, 0.f};

  for (int kt = 0; kt < 9; ++kt){
    int koff = kt * 64;
    __syncthreads();
    #pragma unroll
    for (int i = 0; i < 4; ++i){
      int l  = i * 256 + tid;
      int r  = l >> 3, j = l & 7;
      int js = j ^ (r & 7);
      const short* ga = Abf + (size_t)(bm + r) * K2 + koff + js * 8;
      const short* gb = Wbf + (size_t)(bn + r) * K1 + koff + js * 8;
      short* la = As + ((i * 256 + w * 64) << 3);
      short* lb = Bs + ((i * 256 + w * 64) << 3);
      __builtin_amdgcn_global_load_lds(
          (const __attribute__((address_space(1))) unsigned*)ga,
          (__attribute__((address_space(3))) unsigned*)la, 16, 0, 0);
      __builtin_amdgcn_global_load_lds(
          (const __attribute__((address_space(1))) unsigned*)gb,
          (__attribute__((address_space(3))) unsigned*)lb, 16, 0, 0);
    }
    __syncthreads();
    #pragma unroll
    for (int ks = 0; ks < 2; ++ks){
      const int co = ((ks * 4 + (lane >> 4)) ^ (lrow & 7)) * 8;
      bf16x8 fa[4], fb[4];
      #pragma unroll
      for (int mi = 0; mi < 4; ++mi)
        fa[mi] = *(const bf16x8*)&As[(wr*64 + mi*16 + lrow) * 64 + co];
      #pragma unroll
      for (int ni = 0; ni < 4; ++ni)
        fb[ni] = *(const bf16x8*)&Bs[(wc*64 + ni*16 + lrow) * 64 + co];
      #pragma unroll
      for (int mi = 0; mi < 4; ++mi)
        #pragma unroll
        for (int ni = 0; ni < 4; ++ni)
          acc[mi][ni] = __builtin_amdgcn_mfma_f32_16x16x32_bf16(
              fa[mi], fb[ni], acc[mi][ni], 0, 0, 0);
    }
  }
  #pragma unroll
  for (int mi = 0; mi < 4; ++mi){
    #pragma unroll
    for (int ni = 0; ni < 4; ++ni){
      int gn = bn + wc*64 + ni*16 + lrow;
      float bv = c1b[gn];
      #pragma unroll
      for (int j = 0; j < 4; ++j){
        int gm = bm + wr*64 + mi*16 + (lane >> 4) * 4 + j;
        if (gm < NN)
          C[(size_t)gm * 256 + gn] = selu_f(acc[mi][ni][j] + bv);
      }
    }
  }
}

// ---------------------------------------------------------------------------
// ff1 via MFMA: ffb[NN][2048] = bf16(relu(hbf @ w1b^T + b1)). K=64 (1 tile).
// Grid (16, 63). LDS-staged coalesced bf16 epilogue (stride FFD).
// ---------------------------------------------------------------------------
__global__ __launch_bounds__(256) void k_ff1_mfma(
    const short* __restrict__ hbf, const short* __restrict__ w1b,
    const float* __restrict__ b1, unsigned short* __restrict__ Cb)
{
  __shared__ __align__(16) short smem[2 * 128 * 64];
  short* As = smem;
  short* Bs = smem + 128 * 64;
  const int tid  = threadIdx.x;
  const int bm = blockIdx.y * 128, bn = blockIdx.x * 128;
  const int w    = tid >> 6, lane = tid & 63;
  const int wr   = w >> 1, wc = w & 1;
  const int lrow = lane & 15;

  f32x4 acc[4][4];
  #pragma unroll
  for (int i = 0; i < 4; ++i)
    #pragma unroll
    for (int j = 0; j < 4; ++j) acc[i][j] = (f32x4){0.f, 0.f, 0.f, 0.f};

  // single K-tile (K = 64)
  #pragma unroll
  for (int i = 0; i < 4; ++i){
    int l  = i * 256 + tid;
    int r  = l >> 3, j = l & 7;
    int js = j ^ (r & 7);
    const short* ga = hbf + (size_t)(bm + r) * 64 + js * 8;
    const short* gb = w1b + (size_t)(bn + r) * 64 + js * 8;
    short* la = As + ((i * 256 + w * 64) << 3);
    short* lb = Bs + ((i * 256 + w * 64) << 3);
    __builtin_amdgcn_global_load_lds(
        (const __attribute__((address_space(1))) unsigned*)ga,
        (__attribute__((address_space(3))) unsigned*)la, 16, 0, 0);
    __builtin_amdgcn_global_load_lds(
        (const __attribute__((address_space(1))) unsigned*)gb,
        (__attribute__((address_space(3))) unsigned*)lb, 16, 0, 0);
  }
  __syncthreads();
  #pragma unroll
  for (int ks = 0; ks < 2; ++ks){
    const int co = ((ks * 4 + (lane >> 4)) ^ (lrow & 7)) * 8;
    bf16x8 fa[4], fb[4];
    #pragma unroll
    for (int mi = 0; mi < 4; ++mi)
      fa[mi] = *(const bf16x8*)&As[(wr*64 + mi*16 + lrow) * 64 + co];
    #pragma unroll
    for (int ni = 0; ni < 4; ++ni)
      fb[ni] = *(const bf16x8*)&Bs[(wc*64 + ni*16 + lrow) * 64 + co];
    #pragma unroll
    for (int mi = 0; mi < 4; ++mi)
      #pragma unroll
      for (int ni = 0; ni < 4; ++ni)
        acc[mi][ni] = __builtin_amdgcn_mfma_f32_16x16x32_bf16(
            fa[mi], fb[ni], acc[mi][ni], 0, 0, 0);
  }
  // epilogue: relu + bf16 via LDS staging, coalesced 16B stores
  __syncthreads();
  unsigned short* Ct = (unsigned short*)smem;
  #pragma unroll
  for (int mi = 0; mi < 4; ++mi){
    #pragma unroll
    for (int ni = 0; ni < 4; ++ni){
      int col = wc*64 + ni*16 + lrow;
      int gn  = bn + col;
      float bv = b1[gn];
      #pragma unroll
      for (int j = 0; j < 4; ++j){
        int row  = wr*64 + mi*16 + (lane >> 4)*4 + j;
        int colp = col ^ (((row >> 2) & 3) << 4);
        Ct[row*128 + colp] = f2bf_rn(fmaxf(acc[mi][ni][j] + bv, 0.f));
      }
    }
  }
  __syncthreads();
  #pragma unroll
  for (int c = 0; c < 8; ++c){
    int g   = c*256 + tid;
    int row = g >> 4, cc = g & 15;
    int ccp = cc ^ (((row >> 2) & 3) << 1);
    int gm  = bm + row;
    if (gm < NN){
      bf16x8 v = *(const bf16x8*)&Ct[row*128 + ccp*8];
      *(bf16x8*)&Cb[(size_t)gm * FFD + bn + cc*8] = v;
    }
  }
}

// ---------------------------------------------------------------------------
// ff2 via MFMA split-K: part[kz][NN][64] = ffb @ w2b^T over K-chunk kz*512.
// w2b padded to 128 rows (64..127 zero); wc==1 waves compute zeros, skip store.
// Grid (1, 63, 4).
// ---------------------------------------------------------------------------
__global__ __launch_bounds__(256) void k_ff2_mfma(
    const unsigned short* __restrict__ ffb, const short* __restrict__ w2b,
    float* __restrict__ part)
{
  __shared__ __align__(16) short smem[2 * 128 * 64];
  short* As = smem;
  short* Bs = smem + 128 * 64;
  const int tid  = threadIdx.x;
  const int bm = blockIdx.y * 128;
  const int kz = blockIdx.z;
  const int w    = tid >> 6, lane = tid & 63;
  const int wr   = w >> 1, wc = w & 1;
  const int lrow = lane & 15;

  f32x4 acc[4][4];
  #pragma unroll
  for (int i = 0; i < 4; ++i)
    #pragma unroll
    for (int j = 0; j < 4; ++j) acc[i][j] = (f32x4){0.f, 0.f, 0.f, 0.f};

  for (int kt = 0; kt < 8; ++kt){
    int koff = kz * 512 + kt * 64;
    __syncthreads();
    #pragma unroll
    for (int i = 0; i < 4; ++i){
      int l  = i * 256 + tid;
      int r  = l >> 3, j = l & 7;
      int js = j ^ (r & 7);
      const short* ga = (const short*)ffb + (size_t)(bm + r) * FFD + koff + js * 8;
      const short* gb = w2b + (size_t)r * FFD + koff + js * 8;
      short* la = As + ((i * 256 + w * 64) << 3);
      short* lb = Bs + ((i * 256 + w * 64) << 3);
      __builtin_amdgcn_global_load_lds(
          (const __attribute__((address_space(1))) unsigned*)ga,
          (__attribute__((address_space(3))) unsigned*)la, 16, 0, 0);
      __builtin_amdgcn_global_load_lds(
          (const __attribute__((address_space(1))) unsigned*)gb,
          (__attribute__((address_space(3))) unsigned*)lb, 16, 0, 0);
    }
    __syncthreads();
    #pragma unroll
    for (int ks = 0; ks < 2; ++ks){
      const int co = ((ks * 4 + (lane >> 4)) ^ (lrow & 7)) * 8;
      bf16x8 fa[4], fb[4];
      #pragma unroll
      for (int mi = 0; mi < 4; ++mi)
        fa[mi] = *(const bf16x8*)&As[(wr*64 + mi*16 + lrow) * 64 + co];
      #pragma unroll
      for (int ni = 0; ni < 4; ++ni)
        fb[ni] = *(const bf16x8*)&Bs[(wc*64 + ni*16 + lrow) * 64 + co];
      #pragma unroll
      for (int mi = 0; mi < 4; ++mi)
        #pragma unroll
        for (int ni = 0; ni < 4; ++ni)
          acc[mi][ni] = __builtin_amdgcn_mfma_f32_16x16x32_bf16(
              fa[mi], fb[ni], acc[mi][ni], 0, 0, 0);
    }
  }
  if (wc == 0){                       // cols 0..63 only (64..127 are zero pad)
    float* pz = part + (size_t)kz * NN * 64;
    #pragma unroll
    for (int mi = 0; mi < 4; ++mi){
      #pragma unroll
      for (int ni = 0; ni < 4; ++ni){
        int gn = ni*16 + lrow;
        #pragma unroll
        for (int j = 0; j < 4; ++j){
          int gm = bm + wr*64 + mi*16 + (lane >> 4) * 4 + j;
          if (gm < NN)
            pz[(size_t)gm * 64 + gn] = acc[mi][ni][j];
        }
      }
    }
  }
}

// ---------------------------------------------------------------------------
// split-K flash attention, stage 1. Defer-max (T13) in log2 domain.
// TWO queries per thread (q, q+1024); KSPLIT=20 (KCH=100).
// ---------------------------------------------------------------------------
__global__ __launch_bounds__(128) void k_attn_part(const float* __restrict__ qkv,
    float* __restrict__ Pm, float* __restrict__ Pl, float* __restrict__ Pacc)
{
  __shared__ float Ks[KCH][DHD];
  __shared__ float Vs[KCH][DHD];
  const int q1 = blockIdx.x * 128 + threadIdx.x;   // 0..1023
  const int q2 = q1 + 1024;                        // 1024..2047
  const int bh = blockIdx.y;
  const int b  = bh >> 2, h = bh & 3;
  const int ks = blockIdx.z;
  const bool v2 = q2 < SEQ;
  const float SC = 0.25f * 1.4426950408889634f;    // scale * log2(e)
  float qv1[DHD], qv2[DHD];
  {
    const float4* qr = (const float4*)(qkv + ((size_t)(b*SEQ + q1))*192 + h*DHD);
    #pragma unroll
    for (int j = 0; j < 4; ++j){
      float4 t = qr[j];
      qv1[j*4+0] = t.x; qv1[j*4+1] = t.y; qv1[j*4+2] = t.z; qv1[j*4+3] = t.w;
    }
  }
  if (v2){
    const float4* qr = (const float4*)(qkv + ((size_t)(b*SEQ + q2))*192 + h*DHD);
    #pragma unroll
    for (int j = 0; j < 4; ++j){
      float4 t = qr[j];
      qv2[j*4+0] = t.x; qv2[j*4+1] = t.y; qv2[j*4+2] = t.z; qv2[j*4+3] = t.w;
    }
  } else {
    #pragma unroll
    for (int j = 0; j < DHD; ++j) qv2[j] = 0.f;
  }
  const int kbeg = ks * KCH;
  for (int el = threadIdx.x; el < KCH * 4; el += 128){
    int r = el >> 2, d4 = el & 3;
    const float4* base = (const float4*)(qkv + ((size_t)(b*SEQ + kbeg + r))*192 + h*DHD);
    ((float4*)Ks[r])[d4] = base[16 + d4];      // +64 floats  = K block
    ((float4*)Vs[r])[d4] = base[32 + d4];      // +128 floats = V block
  }
  __syncthreads();
  float m1 = -1e30f, l1 = 0.f, a1[DHD] = {};
  float m2 = -1e30f, l2 = 0.f, a2[DHD] = {};
  for (int r = 0; r < KCH; ++r){
    float s1 = 0.f, s2 = 0.f;
    #pragma unroll
    for (int d = 0; d < DHD; ++d){
      float kd = Ks[r][d];
      s1 = fmaf(qv1[d], kd, s1);
      s2 = fmaf(qv2[d], kd, s2);
    }
    s1 *= SC; s2 *= SC;
    if (__any((s1 > m1 + 8.f) || (s2 > m2 + 8.f))){
      float mn1 = fmaxf(m1, s1), mn2 = fmaxf(m2, s2);
      float c1 = exp2f(m1 - mn1), c2 = exp2f(m2 - mn2);
      l1 *= c1; l2 *= c2;
      #pragma unroll
      for (int d = 0; d < DHD; ++d){ a1[d] *= c1; a2[d] *= c2; }
      m1 = mn1; m2 = mn2;
    }
    float p1 = exp2f(s1 - m1), p2 = exp2f(s2 - m2);
    l1 += p1; l2 += p2;
    #pragma unroll
    for (int d = 0; d < DHD; ++d){
      float vd = Vs[r][d];
      a1[d] = fmaf(p1, vd, a1[d]);
      a2[d] = fmaf(p2, vd, a2[d]);
    }
  }
  {
    size_t qi = ((size_t)bh * SEQ + q1) * KSPLIT + ks;
    Pm[qi] = m1; Pl[qi] = l1;
    #pragma unroll
    for (int d = 0; d < DHD; ++d) Pacc[qi*DHD + d] = a1[d];
  }
  if (v2){
    size_t qi = ((size_t)bh * SEQ + q2) * KSPLIT + ks;
    Pm[qi] = m2; Pl[qi] = l2;
    #pragma unroll
    for (int d = 0; d < DHD; ++d) Pacc[qi*DHD + d] = a2[d];
  }
}

// stage 2: merge KSPLIT partials per query -> o[N][64] (log2 domain)
__global__ void k_attn_comb(const float* __restrict__ Pm, const float* __restrict__ Pl,
                            const float* __restrict__ Pacc, float* __restrict__ o)
{
  int qi = blockIdx.x * blockDim.x + threadIdx.x;
  if (qi >= BATCH * NHTR * SEQ) return;
  float m = -1e30f;
  #pragma unroll
  for (int ks = 0; ks < KSPLIT; ++ks) m = fmaxf(m, Pm[(size_t)qi*KSPLIT + ks]);
  float l = 0.f, acc[DHD] = {};
  #pragma unroll
  for (int ks = 0; ks < KSPLIT; ++ks){
    size_t p = (size_t)qi*KSPLIT + ks;
    float sc = exp2f(Pm[p] - m);
    l += Pl[p] * sc;
    #pragma unroll
    for (int d = 0; d < DHD; ++d) acc[d] = fmaf(Pacc[p*DHD + d], sc, acc[d]);
  }
  int bh = qi / SEQ, q = qi - bh * SEQ;
  int b = bh >> 2, h = bh & 3;
  float inv = 1.f / l;
  #pragma unroll
  for (int d = 0; d < DHD; ++d)
    o[((size_t)(b*SEQ + q))*64 + h*DHD + d] = acc[d] * inv;
}

// ---------------------------------------------------------------------------
// addln that also emits bf16 copy of the output (feeds ff1's MFMA A operand).
// ---------------------------------------------------------------------------
__global__ __launch_bounds__(256) void k_addln(const float* __restrict__ x,
    const float* __restrict__ y, const float* __restrict__ g,
    const float* __restrict__ b, float* __restrict__ out,
    short* __restrict__ hbf)
{
  int row = blockIdx.x * 4 + (threadIdx.x >> 6);
  int lane = threadIdx.x & 63;
  if (row >= NN) return;
  float v = x[(size_t)row*64 + lane] + y[(size_t)row*64 + lane];
  float s1 = v, s2 = v * v;
  #pragma unroll
  for (int o = 32; o; o >>= 1){ s1 += __shfl_xor(s1, o); s2 += __shfl_xor(s2, o); }
  float mean = s1 * (1.f/64.f);
  float var  = s2 * (1.f/64.f) - mean * mean;
  float r = rsqrtf(var + 1e-5f);
  float res = (v - mean) * r * g[lane] + b[lane];
  out[(size_t)row*64 + lane] = res;
  hbf[(size_t)row*64 + lane] = (short)f2bf_rn(res);
}

// feats + coord init in one pass (both read xin)
__global__ void k_prep(const float* __restrict__ x, const float* __restrict__ tout,
                       float* __restrict__ feats, float* __restrict__ coord)
{
  int i = blockIdx.x * blockDim.x + threadIdx.x;
  if (i >= NN * 23) return;
  int n = i / 23, c = i - 23*n;
  if (c < 21)
    feats[(size_t)n*21 + c] = (c < 5) ? x[(size_t)n*7 + 2 + c] : tout[(size_t)n*16 + c - 5];
  else
    coord[(size_t)n*2 + (c - 21)] = x[(size_t)n*7 + (c - 21)];
}

// zero hbf pad rows once
__global__ void k_zpad(short* __restrict__ hbf)
{
  int i = blockIdx.x * blockDim.x + threadIdx.x;
  if (i >= (MPAD - NN) * 64) return;
  hbf[(size_t)NN*64 + i] = 0;
}

// ---------------------------------------------------------------------------
// CSR build (by dst). dst for e>=NEDGE is the self-loop e-NEDGE.
// ---------------------------------------------------------------------------
__global__ void k_count(const int* __restrict__ dst, int* __restrict__ cnt)
{
  int e = blockIdx.x * blockDim.x + threadIdx.x;
  if (e >= ELOOP) return;
  int d = (e < NEDGE) ? dst[e] : e - NEDGE;
  atomicAdd(&cnt[d], 1);
}

__global__ __launch_bounds__(1024) void k_scan(const int* __restrict__ cnt,
                                               int* __restrict__ ptr)
{
  __shared__ int part[1024];
  int tid = threadIdx.x;
  const int per = 8;
  int loc[per]; int s = 0;
  int base = tid * per;
  #pragma unroll
  for (int i = 0; i < per; ++i){
    int v = (base + i < NN) ? cnt[base + i] : 0;
    loc[i] = s; s += v;
  }
  part[tid] = s;
  __syncthreads();
  for (int off = 1; off < 1024; off <<= 1){
    int v = 0;
    if (tid >= off) v = part[tid - off];
    __syncthreads();
    if (tid >= off) part[tid] += v;
    __syncthreads();
  }
  int pre = tid ? part[tid - 1] : 0;
  #pragma unroll
  for (int i = 0; i < per; ++i)
    if (base + i < NN) ptr[base + i] = pre + loc[i];
  if (tid == 1023) ptr[NN] = part[1023];
}

__global__ void k_fill(const int* __restrict__ dst, const int* __restrict__ ptr,
                       int* __restrict__ fil, int* __restrict__ eid)
{
  int e = blockIdx.x * blockDim.x + threadIdx.x;
  if (e >= ELOOP) return;
  int d = (e < NEDGE) ? dst[e] : e - NEDGE;
  int pos = ptr[d] + atomicAdd(&fil[d], 1);
  eid[pos] = e;
}

// ---------------------------------------------------------------------------
// FUSED edge phase (replaces k_logits + k_stats + k_agg): one block per dst
// node; single pass over incoming edges with online (flash-style) softmax.
// Per edge: load xl[src] row once (6 uints/thread, head k = uint tid+k*256),
// block-reduce the 6 per-head logits, then rescale-accumulate into acc[12].
// xr[n] and att are block-constant -> hoisted to registers.
// hidden[n,c] = selu(mean_h acc_h[c]/l_h + gbias[c]); abf refresh.
// ---------------------------------------------------------------------------
__global__ __launch_bounds__(256) void k_aggf(const unsigned short* __restrict__ xc,
    const int* __restrict__ ptr, const int* __restrict__ eid,
    const int* __restrict__ src_a, const float* __restrict__ att,
    const float* __restrict__ gbias, float* __restrict__ hidden,
    short* __restrict__ abf)
{
  const int n = blockIdx.x;
  const int tid = threadIdx.x;
  const int lane = tid & 63, wv = tid >> 6;
  __shared__ int   src_sh[64];
  __shared__ float redl[24];          // 4 waves x 6 heads
  const int s0 = ptr[n];
  const int deg = ptr[n + 1] - s0;

  // block-constant per-thread values: xr channels (2t,2t+1 of head k), att
  float xr0[6], xr1[6], at0[6], at1[6];
  const unsigned* xrrow = (const unsigned*)(xc + (size_t)n * GOUT2 + GOUT);
  #pragma unroll
  for (int k = 0; k < 6; ++k){
    unsigned ur = xrrow[tid + (k << 8)];
    xr0[k] = __uint_as_float(ur << 16);
    xr1[k] = __uint_as_float(ur & 0xffff0000u);
    at0[k] = att[k*512 + 2*tid];
    at1[k] = att[k*512 + 2*tid + 1];
  }
  float mh[6], lh[6], acc[12];
  #pragma unroll
  for (int k = 0; k < 6; ++k){ mh[k] = -1e30f; lh[k] = 0.f; }
  #pragma unroll
  for (int j = 0; j < 12; ++j) acc[j] = 0.f;

  for (int base = 0; base < deg; base += 64){
    int cnt = min(64, deg - base);
    __syncthreads();                  // protect src_sh reuse
    if (tid < cnt){
      int e = eid[s0 + base + tid];
      src_sh[tid] = (e < NEDGE) ? src_a[e] : e - NEDGE;
    }
    __syncthreads();
    for (int i2 = 0; i2 < cnt; ++i2){
      const unsigned* row = (const unsigned*)(xc + (size_t)src_sh[i2] * GOUT2);
      unsigned u[6];
      float part[6];
      #pragma unroll
      for (int k = 0; k < 6; ++k){
        unsigned uu = row[tid + (k << 8)];
        u[k] = uu;
        float v0 = __uint_as_float(uu << 16)         + xr0[k];
        float v1 = __uint_as_float(uu & 0xffff0000u) + xr1[k];
        v0 = v0 > 0.f ? v0 : 0.2f * v0;
        v1 = v1 > 0.f ? v1 : 0.2f * v1;
        part[k] = fmaf(v0, at0[k], v1 * at1[k]);
      }
      #pragma unroll
      for (int k = 0; k < 6; ++k){
        float p = part[k];
        #pragma unroll
        for (int o2 = 32; o2; o2 >>= 1) p += __shfl_xor(p, o2);
        if (lane == 0) redl[wv*6 + k] = p;
      }
      __syncthreads();
      #pragma unroll
      for (int k = 0; k < 6; ++k){
        float lg = redl[k] + redl[6 + k] + redl[12 + k] + redl[18 + k];
        float mn = fmaxf(mh[k], lg);
        float sc = __expf(mh[k] - mn);
        float w  = __expf(lg - mn);
        lh[k] = fmaf(lh[k], sc, w);
        acc[2*k]   = fmaf(acc[2*k],   sc, w * __uint_as_float(u[k] << 16));
        acc[2*k+1] = fmaf(acc[2*k+1], sc, w * __uint_as_float(u[k] & 0xffff0000u));
        mh[k] = mn;
      }
      __syncthreads();                // protect redl before next edge
    }
  }
  float s0a = 0.f, s1a = 0.f;
  #pragma unroll
  for (int k = 0; k < 6; ++k){
    float inv = 1.f / lh[k];
    s0a = fmaf(acc[2*k],   inv, s0a);
    s1a = fmaf(acc[2*k+1], inv, s1a);
  }
  float2 out;
  out.x = selu_f(s0a * (1.f/6.f) + gbias[2*tid]);
  out.y = selu_f(s1a * (1.f/6.f) + gbias[2*tid + 1]);
  *(float2*)&hidden[(size_t)n*HIDD + 2*tid] = out;
  unsigned short h0 = f2bf_rn(out.x), h1 = f2bf_rn(out.y);
  *(unsigned*)&abf[(size_t)n*K2 + 2 + 2*tid] = (unsigned)h0 | ((unsigned)h1 << 16);
}

// ---------------------------------------------------------------------------
extern "C" void kernel_launch(void* const* d_in, const int* in_sizes, int n_in,
                              void* d_out, int out_size, void* d_ws, size_t ws_size,
                              hipStream_t stream)
{
  const float* mesh     = (const float*)d_in[1];
  const float* xin      = (const float*)d_in[2];
  const int*   ei       = (const int*)d_in[3];
  const float* embed_w  = (const float*)d_in[4];
  const float* embed_b  = (const float*)d_in[5];
  const float* in_proj_w= (const float*)d_in[6];
  const float* in_proj_b= (const float*)d_in[7];
  const float* out_proj_w=(const float*)d_in[8];
  const float* out_proj_b=(const float*)d_in[9];
  const float* ln1_g    = (const float*)d_in[10];
  const float* ln1_b    = (const float*)d_in[11];
  const float* ln2_g    = (const float*)d_in[12];
  const float* ln2_b    = (const float*)d_in[13];
  const float* ff1_w    = (const float*)d_in[14];
  const float* ff1_b    = (const float*)d_in[15];
  const float* ff2_w    = (const float*)d_in[16];
  const float* ff2_b    = (const float*)d_in[17];
  const float* tout_w   = (const float*)d_in[18];
  const float* tout_b   = (const float*)d_in[19];
  const float* lin_w    = (const float*)d_in[20];
  const float* lin_b    = (const float*)d_in[21];
  const float* gat_wl   = (const float*)d_in[22];
  const float* gat_bl   = (const float*)d_in[23];
  const float* gat_wr   = (const float*)d_in[24];
  const float* gat_br   = (const float*)d_in[25];
  const float* gat_att  = (const float*)d_in[26];
  const float* gat_bias = (const float*)d_in[27];
  const float* coord1_w = (const float*)d_in[28];
  const float* coord1_b = (const float*)d_in[29];
  const float* coord2_w = (const float*)d_in[30];
  const float* coord2_b = (const float*)d_in[31];

  const int* esrc = ei;
  const int* edst = ei + NEDGE;

  char* ws = (char*)d_ws;
  size_t off = 0;
  auto alloc = [&](size_t nbytes){
    size_t o = off; off += (nbytes + 255) & ~(size_t)255; return o;
  };
  float* hidden = (float*)(ws + alloc((size_t)NN * HIDD * 4));
  float* coord  = (float*)(ws + alloc((size_t)NN * 2 * 4));
  unsigned short* xc = (unsigned short*)(ws + alloc((size_t)NN * GOUT2 * 2));  // 93.75 MiB
  int*   ptr    = (int*)(ws + alloc((size_t)(NN + 1) * 4));
  int*   eid    = (int*)(ws + alloc((size_t)ELOOP * 4));
  int*   cnt    = (int*)(ws + alloc((size_t)NN * 4));
  int*   fil    = (int*)(ws + alloc((size_t)NN * 4));
  short* abf    = (short*)(ws + alloc((size_t)MPAD * K2 * 2));
  short* wlbf   = (short*)(ws + alloc((size_t)GOUT * K1 * 2));   // contiguous:
  short* wrbf   = (short*)(ws + alloc((size_t)GOUT * K1 * 2));   // wrbf = wlbf + GOUT*K1
  short* wcb    = (short*)(ws + alloc((size_t)256 * K1 * 2));    // coord1 bf16
  short* w1b    = (short*)(ws + alloc((size_t)FFD * 64 * 2));    // ff1 bf16
  short* w2b    = (short*)(ws + alloc((size_t)128 * FFD * 2));   // ff2 bf16 (padded)
  short* hbf    = (short*)(ws + alloc((size_t)MPAD * 64 * 2));   // h bf16
  float* c1     = (float*)(ws + alloc((size_t)NN * 256 * 4));    // 7.8 MiB
  float* Wp     = (float*)(ws + alloc((size_t)192 * 4 * 4));
  float* bp     = (float*)(ws + alloc((size_t)192 * 4));

  // Transformer-phase temporaries ALIASED inside xc (93.75 MiB).
  char* arena = (char*)xc;
  float* h       = (float*)(arena + ((size_t)0  << 20));  // 0-2     (live to ln2)
  float* o       = (float*)(arena + ((size_t)2  << 20));  // 2-4
  float* tmp     = (float*)(arena + ((size_t)4  << 20));  // 4-6
  float* feats   = (float*)(arena + ((size_t)6  << 20));  // 6-6.7
  float* toutb   = (float*)(arena + ((size_t)7  << 20));  // 7-7.6
  float* qkv     = (float*)(arena + ((size_t)8  << 20));  // 8-14.2  (dead after attn)
  float* Pm      = (float*)(arena + ((size_t)15 << 20));  // 15-17.5 (KSPLIT=20)
  float* Pl      = (float*)(arena + ((size_t)18 << 20));  // 18-20.5
  float* Pacc    = (float*)(arena + ((size_t)21 << 20));  // 21-62   (dead after comb)
  unsigned short* ffb = (unsigned short*)(arena + ((size_t)28 << 20)); // 28-61 (Pacc dead)
  float* part_f2 = (float*)(arena + ((size_t)62 << 20));  // 62-70.2 (free)

  // ---- once: weight conversions + CSR ----
  k_wfuse<<<1, 192, 0, stream>>>(in_proj_w, in_proj_b, embed_w, embed_b, Wp, bp);
  k_cvt_w1<<<CDIV(FFD*64, 256), 256, 0, stream>>>(ff1_w, w1b);
  k_cvt_w2<<<CDIV(128*FFD, 256), 256, 0, stream>>>(ff2_w, w2b);
  k_zpad<<<CDIV((MPAD-NN)*64, 256), 256, 0, stream>>>(hbf);
  hipMemsetAsync(cnt, 0, (size_t)NN * 4, stream);
  hipMemsetAsync(fil, 0, (size_t)NN * 4, stream);
  k_count<<<CDIV(ELOOP, 256), 256, 0, stream>>>(edst, cnt);
  k_scan<<<1, 1024, 0, stream>>>(cnt, ptr);
  k_fill<<<CDIV(ELOOP, 256), 256, 0, stream>>>(edst, ptr, fil, eid);
  k_cvt_w<<<CDIV(GOUT*K1, 256), 256, 0, stream>>>(gat_wl, wlbf);
  k_cvt_w<<<CDIV(GOUT*K1, 256), 256, 0, stream>>>(gat_wr, wrbf);
  k_cvt_wc<<<CDIV(256*K1, 256), 256, 0, stream>>>(coord1_w, wcb);

  // ---- transformer ----
  k_embqkv<<<NN, 256, 0, stream>>>(mesh, embed_w, embed_b, Wp, bp, h, qkv);
  k_attn_part<<<dim3(CDIV(SEQ,256), BATCH*NHTR, KSPLIT), 128, 0, stream>>>(qkv, Pm, Pl, Pacc);
  k_attn_comb<<<CDIV(BATCH*NHTR*SEQ, 256), 256, 0, stream>>>(Pm, Pl, Pacc, o);
  k_gemm<0><<<dim3(1, CDIV(NN,64)), 256, 0, stream>>>(o, out_proj_w, out_proj_b, tmp, NN, 64, 64);
  k_addln<<<CDIV(NN,4), 256, 0, stream>>>(h, tmp, ln1_g, ln1_b, h, hbf);
  k_ff1_mfma<<<dim3(16, 63), 256, 0, stream>>>(hbf, w1b, ff1_b, ffb);
  k_ff2_mfma<<<dim3(1, 63, 4), 256, 0, stream>>>(ffb, w2b, part_f2);
  k_addln4<<<CDIV(NN,4), 256, 0, stream>>>(h, part_f2, ff2_b, ln2_g, ln2_b, h);
  k_gemm<0><<<dim3(1, CDIV(NN,64)), 256, 0, stream>>>(h, tout_w, tout_b, toutb, NN, TOUTD, DTR);
  k_prep<<<CDIV(NN*23, 256), 256, 0, stream>>>(xin, toutb, feats, coord);
  k_gemm<2><<<dim3(CDIV(HIDD,64), CDIV(NN,64)), 256, 0, stream>>>(feats, lin_w, lin_b, hidden, NN, HIDD, 21);
  k_cvt_a<<<CDIV(MPAD*K1, 256), 256, 0, stream>>>(coord, hidden, abf);  // once

  // ---- GAT loops (abf refreshed in-place by k_aggf / k_coord2) ----
  for (int it = 0; it < 3; ++it){
    k_gat_mfma<<<dim3(48, 63), 256, 0, stream>>>(abf, wlbf, gat_bl, gat_br, xc);
    k_aggf<<<NN, 256, 0, stream>>>(xc, ptr, eid, esrc, gat_att, gat_bias, hidden, abf);
    k_c1_mfma<<<dim3(2, 63), 256, 0, stream>>>(abf, wcb, coord1_b, c1);
    float* cdst = (it == 2) ? (float*)d_out : coord;
    k_coord2<<<NN, 256, 0, stream>>>(c1, coord2_w, coord2_b, cdst, abf);
  }
}

// Round 26
// 790.689 us; speedup vs baseline: 1.1787x; 1.1787x over previous
//
#include <hip/hip_runtime.h>
#include <hip/hip_bf16.h>
#include <math.h>

#define NN     8000
#define MPAD   8064    /* NN padded to 128 */
#define BATCH  4
#define SEQ    2000
#define DTR    64
#define NHTR   4
#define DHD    16
#define FFD    2048
#define TOUTD  16
#define HIDD   512
#define NHEADS 6
#define HCD    512
#define GIND   514
#define GOUT   3072
#define GOUT2  6144    /* combined xl|xr row stride */
#define NEDGE  32000
#define ELOOP  40000   /* NEDGE + NN */

#define K1     576     /* GIND padded to 64-multiple */
#define K2     1152    /* abf row stride */

#define KSPLIT 20
#define KCH    100     /* SEQ / KSPLIT */

#define CDIV(a,b) (((a)+(b)-1)/(b))

using bf16x8 = __attribute__((__ext_vector_type__(8))) __bf16;
using f32x4  = __attribute__((__ext_vector_type__(4))) float;

__device__ __forceinline__ float selu_f(float x){
  const float a = 1.6732632423543772848f;
  const float s = 1.0507009873554805f;
  return x > 0.f ? s * x : s * a * (__expf(x) - 1.f);
}

__device__ __forceinline__ unsigned short f2bf_rn(float x){
  unsigned u = __float_as_uint(x);
  unsigned r = (u + 0x7fffu + ((u >> 16) & 1u)) >> 16;
  return (unsigned short)r;
}
__device__ __forceinline__ float bf2f(unsigned short h){
  return __uint_as_float((unsigned)h << 16);
}

// ---------------------------------------------------------------------------
// Generic C[M,N] = act(A[M,K] @ W[N,K]^T + bias). fp32, 64x64 tile, BK=16.
// (out_proj, tout, lin)
// ---------------------------------------------------------------------------
template<int ACT>  // 0=none 1=relu 2=selu
__global__ __launch_bounds__(256) void k_gemm(const float* __restrict__ A,
    const float* __restrict__ W, const float* __restrict__ bias,
    float* __restrict__ C, int M, int N, int K)
{
  __shared__ float As[16][68];
  __shared__ float Ws[16][68];
  const int tid = threadIdx.x;
  const int bm = blockIdx.y * 64, bn = blockIdx.x * 64;
  const int tx = tid & 15, ty = tid >> 4;
  float acc[4][4] = {};
  for (int k0 = 0; k0 < K; k0 += 16){
    #pragma unroll
    for (int i = 0; i < 4; ++i){
      int el = tid + (i << 8);
      int kk = el & 15, r = el >> 4;
      int gk = k0 + kk;
      int gm = bm + r;
      As[kk][r] = (gm < M && gk < K) ? A[(size_t)gm * K + gk] : 0.f;
      int gn = bn + r;
      Ws[kk][r] = (gn < N && gk < K) ? W[(size_t)gn * K + gk] : 0.f;
    }
    __syncthreads();
    #pragma unroll
    for (int kk = 0; kk < 16; ++kk){
      float av[4], wv[4];
      #pragma unroll
      for (int i = 0; i < 4; ++i) av[i] = As[kk][ty*4+i];
      #pragma unroll
      for (int j = 0; j < 4; ++j) wv[j] = Ws[kk][tx*4+j];
      #pragma unroll
      for (int i = 0; i < 4; ++i)
        #pragma unroll
        for (int j = 0; j < 4; ++j) acc[i][j] = fmaf(av[i], wv[j], acc[i][j]);
    }
    __syncthreads();
  }
  #pragma unroll
  for (int i = 0; i < 4; ++i){
    int gm = bm + ty*4 + i;
    if (gm >= M) continue;
    #pragma unroll
    for (int j = 0; j < 4; ++j){
      int gn = bn + tx*4 + j;
      if (gn >= N) continue;
      float v = acc[i][j] + bias[gn];
      if (ACT == 1) v = fmaxf(v, 0.f);
      if (ACT == 2) v = selu_f(v);
      C[(size_t)gm * N + gn] = v;
    }
  }
}

// ---------------------------------------------------------------------------
// fused: out = LN(x + (bias + sum_z part[z])) * g + b   (ff2 tail + addln)
// ---------------------------------------------------------------------------
__global__ __launch_bounds__(256) void k_addln4(const float* __restrict__ x,
    const float* __restrict__ part, const float* __restrict__ bias,
    const float* __restrict__ g, const float* __restrict__ b,
    float* __restrict__ out)
{
  int row = blockIdx.x * 4 + (threadIdx.x >> 6);
  int lane = threadIdx.x & 63;
  if (row >= NN) return;
  float y = bias[lane];
  #pragma unroll
  for (int z = 0; z < 4; ++z) y += part[(size_t)z*NN*DTR + (size_t)row*64 + lane];
  float v = x[(size_t)row*64 + lane] + y;
  float s1 = v, s2 = v * v;
  #pragma unroll
  for (int o = 32; o; o >>= 1){ s1 += __shfl_xor(s1, o); s2 += __shfl_xor(s2, o); }
  float mean = s1 * (1.f/64.f);
  float var  = s2 * (1.f/64.f) - mean * mean;
  float r = rsqrtf(var + 1e-5f);
  out[(size_t)row*64 + lane] = (v - mean) * r * g[lane] + b[lane];
}

// ---------------------------------------------------------------------------
// coord tail: coord[n] = c1row . w2 + b2; refresh abf coord cols (0,1).
// ---------------------------------------------------------------------------
__global__ __launch_bounds__(256) void k_coord2(const float* __restrict__ c1,
    const float* __restrict__ w2, const float* __restrict__ b2,
    float* __restrict__ out, short* __restrict__ abf)
{
  int n = blockIdx.x, t = threadIdx.x;
  float v = c1[(size_t)n*256 + t];
  float d0 = v * w2[t], d1 = v * w2[256 + t];
  #pragma unroll
  for (int o = 32; o; o >>= 1){ d0 += __shfl_xor(d0, o); d1 += __shfl_xor(d1, o); }
  __shared__ float red[8];
  int wv = t >> 6;
  if ((t & 63) == 0){ red[wv] = d0; red[4 + wv] = d1; }
  __syncthreads();
  if (t < 2){
    float c = (t == 0 ? red[0]+red[1]+red[2]+red[3] + b2[0]
                      : red[4]+red[5]+red[6]+red[7] + b2[1]);
    out[(size_t)n*2 + t] = c;
    abf[(size_t)n*K2 + t] = (short)f2bf_rn(c);
  }
}

// ---------------------------------------------------------------------------
// weight fp32 [3072][514] -> single bf16 (RN) [3072][K1]
// ---------------------------------------------------------------------------
__global__ void k_cvt_w(const float* __restrict__ W, short* __restrict__ Wbf)
{
  int i = blockIdx.x * blockDim.x + threadIdx.x;
  if (i >= GOUT * K1) return;
  int n = i / K1, k = i - K1 * n;
  float v = (k < GIND) ? W[(size_t)n * GIND + k] : 0.f;
  Wbf[i] = (short)f2bf_rn(v);
}

// coord1_w fp32 [256][512] -> bf16 [256][K1] (cols 2..513; 0,1 & 514.. zero)
__global__ void k_cvt_wc(const float* __restrict__ W, short* __restrict__ Wbf)
{
  int i = blockIdx.x * blockDim.x + threadIdx.x;
  if (i >= 256 * K1) return;
  int n = i / K1, k = i - K1 * n;
  float v = (k >= 2 && k < GIND) ? W[(size_t)n * HIDD + (k - 2)] : 0.f;
  Wbf[i] = (short)f2bf_rn(v);
}

// ff1_w fp32 [2048][64] -> bf16
__global__ void k_cvt_w1(const float* __restrict__ W, short* __restrict__ Wbf)
{
  int i = blockIdx.x * blockDim.x + threadIdx.x;
  if (i >= FFD * 64) return;
  Wbf[i] = (short)f2bf_rn(W[i]);
}

// ff2_w fp32 [64][2048] -> bf16 [128][2048] (rows 64..127 zero)
__global__ void k_cvt_w2(const float* __restrict__ W, short* __restrict__ Wbf)
{
  int i = blockIdx.x * blockDim.x + threadIdx.x;
  if (i >= 128 * FFD) return;
  int n = i / FFD;
  Wbf[i] = (short)f2bf_rn(n < 64 ? W[i] : 0.f);
}

// A = [coord | hidden] fp32 -> bf16 (RN) [MPAD][K2] (cols 0..K1-1 used).
__global__ void k_cvt_a(const float* __restrict__ coord,
                        const float* __restrict__ hidden,
                        short* __restrict__ Abf)
{
  int i = blockIdx.x * blockDim.x + threadIdx.x;
  if (i >= MPAD * K1) return;
  int n = i / K1, k = i - K1 * n;
  float v = 0.f;
  if (n < NN && k < GIND)
    v = (k < 2) ? coord[(size_t)n*2 + k] : hidden[(size_t)n*HIDD + k - 2];
  Abf[(size_t)n * K2 + k] = (short)f2bf_rn(v);
}

// ---------------------------------------------------------------------------
// Fused embed∘in_proj weight precompute (run once).
// ---------------------------------------------------------------------------
__global__ void k_wfuse(const float* __restrict__ ipw, const float* __restrict__ ipb,
                        const float* __restrict__ ew, const float* __restrict__ eb,
                        float* __restrict__ Wp, float* __restrict__ bp)
{
  int c = blockIdx.x * blockDim.x + threadIdx.x;
  if (c >= 192) return;
  float w4[4] = {0.f, 0.f, 0.f, 0.f};
  float bb = 0.f;
  for (int d = 0; d < 64; ++d){
    float wq = ipw[c*64 + d];
    #pragma unroll
    for (int j = 0; j < 4; ++j) w4[j] = fmaf(wq, ew[d*4 + j], w4[j]);
    bb = fmaf(wq, eb[d], bb);
  }
  #pragma unroll
  for (int j = 0; j < 4; ++j) Wp[c*4 + j] = w4[j];
  bp[c] = bb + ipb[c];
}

// h[n][d] (d<64) and qkv[n][c] (c<192) directly from mesh (4-FMA dots).
__global__ __launch_bounds__(256) void k_embqkv(const float* __restrict__ mesh,
    const float* __restrict__ ew, const float* __restrict__ eb,
    const float* __restrict__ Wp, const float* __restrict__ bp,
    float* __restrict__ h, float* __restrict__ qkv)
{
  int n = blockIdx.x, t = threadIdx.x;
  float m0 = mesh[n*4+0], m1 = mesh[n*4+1], m2 = mesh[n*4+2], m3 = mesh[n*4+3];
  if (t < 64){
    const float* wr = ew + t*4;
    h[(size_t)n*64 + t] =
      fmaf(m0, wr[0], fmaf(m1, wr[1], fmaf(m2, wr[2], m3*wr[3]))) + eb[t];
  } else {
    int c = t - 64;
    const float* wr = Wp + c*4;
    qkv[(size_t)n*192 + c] =
      fmaf(m0, wr[0], fmaf(m1, wr[1], fmaf(m2, wr[2], m3*wr[3]))) + bp[c];
  }
}

// ---------------------------------------------------------------------------
// Merged GAT GEMM via MFMA bf16: C[NN][6144] = A @ [Wl|Wr]^T (+bl|br).
// 9 K-tiles of 64. LDS XOR swizzle both-sides. LDS-staged coalesced epilogue.
// 2D XCD partition: each XCD owns a 6-n-block column band (L2-resident B).
// ---------------------------------------------------------------------------
__global__ __launch_bounds__(256) void k_gat_mfma(
    const short* __restrict__ Abf, const short* __restrict__ Wbf,
    const float* __restrict__ bl, const float* __restrict__ br,
    unsigned short* __restrict__ Cb)
{
  __shared__ __align__(16) short smem[2 * 128 * 64];
  short* As = smem;
  short* Bs = smem + 128 * 64;
  const int tid  = threadIdx.x;
  int lin = blockIdx.y * 48 + blockIdx.x;          // 0..3023
  int xcd = lin & 7;                               // XCD id
  int idx = lin >> 3;                              // 0..377 within XCD
  int nb  = xcd * 6 + idx % 6;                     // fixed 6-col band per XCD
  int mb  = idx / 6;                               // sweep m
  const int bm = mb * 128, bn = nb * 128;
  const int w    = tid >> 6, lane = tid & 63;
  const int wr   = w >> 1, wc = w & 1;
  const int lrow = lane & 15;

  f32x4 acc[4][4];
  #pragma unroll
  for (int i = 0; i < 4; ++i)
    #pragma unroll
    for (int j = 0; j < 4; ++j) acc[i][j] = (f32x4){0.f, 0.f, 0.f, 0.f};

  for (int kt = 0; kt < 9; ++kt){
    int koff = kt * 64;
    __syncthreads();                 // previous tile fully consumed
    #pragma unroll
    for (int i = 0; i < 4; ++i){
      int l  = i * 256 + tid;        // 16B-chunk index 0..1023
      int r  = l >> 3, j = l & 7;
      int js = j ^ (r & 7);          // source pre-swizzle (write side)
      const short* ga = Abf + (size_t)(bm + r) * K2 + koff + js * 8;
      const short* gb = Wbf + (size_t)(bn + r) * K1 + koff + js * 8;
      short* la = As + ((i * 256 + w * 64) << 3);   // wave-uniform base
      short* lb = Bs + ((i * 256 + w * 64) << 3);
      __builtin_amdgcn_global_load_lds(
          (const __attribute__((address_space(1))) unsigned*)ga,
          (__attribute__((address_space(3))) unsigned*)la, 16, 0, 0);
      __builtin_amdgcn_global_load_lds(
          (const __attribute__((address_space(1))) unsigned*)gb,
          (__attribute__((address_space(3))) unsigned*)lb, 16, 0, 0);
    }
    __syncthreads();                 // drains vmcnt, tile ready
    #pragma unroll
    for (int ks = 0; ks < 2; ++ks){
      const int co = ((ks * 4 + (lane >> 4)) ^ (lrow & 7)) * 8;
      bf16x8 fa[4], fb[4];
      #pragma unroll
      for (int mi = 0; mi < 4; ++mi)
        fa[mi] = *(const bf16x8*)&As[(wr*64 + mi*16 + lrow) * 64 + co];
      #pragma unroll
      for (int ni = 0; ni < 4; ++ni)
        fb[ni] = *(const bf16x8*)&Bs[(wc*64 + ni*16 + lrow) * 64 + co];
      #pragma unroll
      for (int mi = 0; mi < 4; ++mi)
        #pragma unroll
        for (int ni = 0; ni < 4; ++ni)
          acc[mi][ni] = __builtin_amdgcn_mfma_f32_16x16x32_bf16(
              fa[mi], fb[ni], acc[mi][ni], 0, 0, 0);
    }
  }
  // ---- epilogue: stage 128x128 bf16 tile in LDS (reuse As|Bs = 32 KB) ----
  __syncthreads();                               // done reading As/Bs
  unsigned short* Ct = (unsigned short*)smem;
  #pragma unroll
  for (int mi = 0; mi < 4; ++mi){
    #pragma unroll
    for (int ni = 0; ni < 4; ++ni){
      int col = wc*64 + ni*16 + lrow;
      int gn  = bn + col;
      float bv = (gn < GOUT) ? bl[gn] : br[gn - GOUT];  // block-uniform branch
      #pragma unroll
      for (int j = 0; j < 4; ++j){
        int row  = wr*64 + mi*16 + (lane >> 4)*4 + j;
        int colp = col ^ (((row >> 2) & 3) << 4);       // bank-spread swizzle
        Ct[row*128 + colp] = f2bf_rn(acc[mi][ni][j] + bv);
      }
    }
  }
  __syncthreads();
  #pragma unroll
  for (int c = 0; c < 8; ++c){
    int g   = c*256 + tid;            // chunk id 0..2047 (16B chunks)
    int row = g >> 4, cc = g & 15;
    int ccp = cc ^ (((row >> 2) & 3) << 1);             // de-swizzle
    int gm  = bm + row;
    if (gm < NN){
      bf16x8 v = *(const bf16x8*)&Ct[row*128 + ccp*8];
      *(bf16x8*)&Cb[(size_t)gm * GOUT2 + bn + cc*8] = v;
    }
  }
}

// ---------------------------------------------------------------------------
// coord1 via MFMA: c1[NN][256] = selu(abf @ wcb^T + c1b). Grid (2, 63).
// ---------------------------------------------------------------------------
__global__ __launch_bounds__(256) void k_c1_mfma(
    const short* __restrict__ Abf, const short* __restrict__ Wbf,
    const float* __restrict__ c1b, float* __restrict__ C)
{
  __shared__ __align__(16) short smem[2 * 128 * 64];
  short* As = smem;
  short* Bs = smem + 128 * 64;
  const int tid  = threadIdx.x;
  const int bm = blockIdx.y * 128, bn = blockIdx.x * 128;
  const int w    = tid >> 6, lane = tid & 63;
  const int wr   = w >> 1, wc = w & 1;
  const int lrow = lane & 15;

  f32x4 acc[4][4];
  #pragma unroll
  for (int i = 0; i < 4; ++i)
    #pragma unroll
    for (int j = 0; j < 4; ++j) acc[i][j] = (f32x4){0.f, 0.f, 0.f, 0.f};

  for (int kt = 0; kt < 9; ++kt){
    int koff = kt * 64;
    __syncthreads();
    #pragma unroll
    for (int i = 0; i < 4; ++i){
      int l  = i * 256 + tid;
      int r  = l >> 3, j = l & 7;
      int js = j ^ (r & 7);
      const short* ga = Abf + (size_t)(bm + r) * K2 + koff + js * 8;
      const short* gb = Wbf + (size_t)(bn + r) * K1 + koff + js * 8;
      short* la = As + ((i * 256 + w * 64) << 3);
      short* lb = Bs + ((i * 256 + w * 64) << 3);
      __builtin_amdgcn_global_load_lds(
          (const __attribute__((address_space(1))) unsigned*)ga,
          (__attribute__((address_space(3))) unsigned*)la, 16, 0, 0);
      __builtin_amdgcn_global_load_lds(
          (const __attribute__((address_space(1))) unsigned*)gb,
          (__attribute__((address_space(3))) unsigned*)lb, 16, 0, 0);
    }
    __syncthreads();
    #pragma unroll
    for (int ks = 0; ks < 2; ++ks){
      const int co = ((ks * 4 + (lane >> 4)) ^ (lrow & 7)) * 8;
      bf16x8 fa[4], fb[4];
      #pragma unroll
      for (int mi = 0; mi < 4; ++mi)
        fa[mi] = *(const bf16x8*)&As[(wr*64 + mi*16 + lrow) * 64 + co];
      #pragma unroll
      for (int ni = 0; ni < 4; ++ni)
        fb[ni] = *(const bf16x8*)&Bs[(wc*64 + ni*16 + lrow) * 64 + co];
      #pragma unroll
      for (int mi = 0; mi < 4; ++mi)
        #pragma unroll
        for (int ni = 0; ni < 4; ++ni)
          acc[mi][ni] = __builtin_amdgcn_mfma_f32_16x16x32_bf16(
              fa[mi], fb[ni], acc[mi][ni], 0, 0, 0);
    }
  }
  #pragma unroll
  for (int mi = 0; mi < 4; ++mi){
    #pragma unroll
    for (int ni = 0; ni < 4; ++ni){
      int gn = bn + wc*64 + ni*16 + lrow;
      float bv = c1b[gn];
      #pragma unroll
      for (int j = 0; j < 4; ++j){
        int gm = bm + wr*64 + mi*16 + (lane >> 4) * 4 + j;
        if (gm < NN)
          C[(size_t)gm * 256 + gn] = selu_f(acc[mi][ni][j] + bv);
      }
    }
  }
}

// ---------------------------------------------------------------------------
// ff1 via MFMA: ffb[NN][2048] = bf16(relu(hbf @ w1b^T + b1)). K=64 (1 tile).
// Grid (16, 63). LDS-staged coalesced bf16 epilogue (stride FFD).
// ---------------------------------------------------------------------------
__global__ __launch_bounds__(256) void k_ff1_mfma(
    const short* __restrict__ hbf, const short* __restrict__ w1b,
    const float* __restrict__ b1, unsigned short* __restrict__ Cb)
{
  __shared__ __align__(16) short smem[2 * 128 * 64];
  short* As = smem;
  short* Bs = smem + 128 * 64;
  const int tid  = threadIdx.x;
  const int bm = blockIdx.y * 128, bn = blockIdx.x * 128;
  const int w    = tid >> 6, lane = tid & 63;
  const int wr   = w >> 1, wc = w & 1;
  const int lrow = lane & 15;

  f32x4 acc[4][4];
  #pragma unroll
  for (int i = 0; i < 4; ++i)
    #pragma unroll
    for (int j = 0; j < 4; ++j) acc[i][j] = (f32x4){0.f, 0.f, 0.f, 0.f};

  // single K-tile (K = 64)
  #pragma unroll
  for (int i = 0; i < 4; ++i){
    int l  = i * 256 + tid;
    int r  = l >> 3, j = l & 7;
    int js = j ^ (r & 7);
    const short* ga = hbf + (size_t)(bm + r) * 64 + js * 8;
    const short* gb = w1b + (size_t)(bn + r) * 64 + js * 8;
    short* la = As + ((i * 256 + w * 64) << 3);
    short* lb = Bs + ((i * 256 + w * 64) << 3);
    __builtin_amdgcn_global_load_lds(
        (const __attribute__((address_space(1))) unsigned*)ga,
        (__attribute__((address_space(3))) unsigned*)la, 16, 0, 0);
    __builtin_amdgcn_global_load_lds(
        (const __attribute__((address_space(1))) unsigned*)gb,
        (__attribute__((address_space(3))) unsigned*)lb, 16, 0, 0);
  }
  __syncthreads();
  #pragma unroll
  for (int ks = 0; ks < 2; ++ks){
    const int co = ((ks * 4 + (lane >> 4)) ^ (lrow & 7)) * 8;
    bf16x8 fa[4], fb[4];
    #pragma unroll
    for (int mi = 0; mi < 4; ++mi)
      fa[mi] = *(const bf16x8*)&As[(wr*64 + mi*16 + lrow) * 64 + co];
    #pragma unroll
    for (int ni = 0; ni < 4; ++ni)
      fb[ni] = *(const bf16x8*)&Bs[(wc*64 + ni*16 + lrow) * 64 + co];
    #pragma unroll
    for (int mi = 0; mi < 4; ++mi)
      #pragma unroll
      for (int ni = 0; ni < 4; ++ni)
        acc[mi][ni] = __builtin_amdgcn_mfma_f32_16x16x32_bf16(
            fa[mi], fb[ni], acc[mi][ni], 0, 0, 0);
  }
  // epilogue: relu + bf16 via LDS staging, coalesced 16B stores
  __syncthreads();
  unsigned short* Ct = (unsigned short*)smem;
  #pragma unroll
  for (int mi = 0; mi < 4; ++mi){
    #pragma unroll
    for (int ni = 0; ni < 4; ++ni){
      int col = wc*64 + ni*16 + lrow;
      int gn  = bn + col;
      float bv = b1[gn];
      #pragma unroll
      for (int j = 0; j < 4; ++j){
        int row  = wr*64 + mi*16 + (lane >> 4)*4 + j;
        int colp = col ^ (((row >> 2) & 3) << 4);
        Ct[row*128 + colp] = f2bf_rn(fmaxf(acc[mi][ni][j] + bv, 0.f));
      }
    }
  }
  __syncthreads();
  #pragma unroll
  for (int c = 0; c < 8; ++c){
    int g   = c*256 + tid;
    int row = g >> 4, cc = g & 15;
    int ccp = cc ^ (((row >> 2) & 3) << 1);
    int gm  = bm + row;
    if (gm < NN){
      bf16x8 v = *(const bf16x8*)&Ct[row*128 + ccp*8];
      *(bf16x8*)&Cb[(size_t)gm * FFD + bn + cc*8] = v;
    }
  }
}

// ---------------------------------------------------------------------------
// ff2 via MFMA split-K: part[kz][NN][64] = ffb @ w2b^T over K-chunk kz*512.
// w2b padded to 128 rows (64..127 zero); wc==1 waves compute zeros, skip store.
// Grid (1, 63, 4).
// ---------------------------------------------------------------------------
__global__ __launch_bounds__(256) void k_ff2_mfma(
    const unsigned short* __restrict__ ffb, const short* __restrict__ w2b,
    float* __restrict__ part)
{
  __shared__ __align__(16) short smem[2 * 128 * 64];
  short* As = smem;
  short* Bs = smem + 128 * 64;
  const int tid  = threadIdx.x;
  const int bm = blockIdx.y * 128;
  const int kz = blockIdx.z;
  const int w    = tid >> 6, lane = tid & 63;
  const int wr   = w >> 1, wc = w & 1;
  const int lrow = lane & 15;

  f32x4 acc[4][4];
  #pragma unroll
  for (int i = 0; i < 4; ++i)
    #pragma unroll
    for (int j = 0; j < 4; ++j) acc[i][j] = (f32x4){0.f, 0.f, 0.f, 0.f};

  for (int kt = 0; kt < 8; ++kt){
    int koff = kz * 512 + kt * 64;
    __syncthreads();
    #pragma unroll
    for (int i = 0; i < 4; ++i){
      int l  = i * 256 + tid;
      int r  = l >> 3, j = l & 7;
      int js = j ^ (r & 7);
      const short* ga = (const short*)ffb + (size_t)(bm + r) * FFD + koff + js * 8;
      const short* gb = w2b + (size_t)r * FFD + koff + js * 8;
      short* la = As + ((i * 256 + w * 64) << 3);
      short* lb = Bs + ((i * 256 + w * 64) << 3);
      __builtin_amdgcn_global_load_lds(
          (const __attribute__((address_space(1))) unsigned*)ga,
          (__attribute__((address_space(3))) unsigned*)la, 16, 0, 0);
      __builtin_amdgcn_global_load_lds(
          (const __attribute__((address_space(1))) unsigned*)gb,
          (__attribute__((address_space(3))) unsigned*)lb, 16, 0, 0);
    }
    __syncthreads();
    #pragma unroll
    for (int ks = 0; ks < 2; ++ks){
      const int co = ((ks * 4 + (lane >> 4)) ^ (lrow & 7)) * 8;
      bf16x8 fa[4], fb[4];
      #pragma unroll
      for (int mi = 0; mi < 4; ++mi)
        fa[mi] = *(const bf16x8*)&As[(wr*64 + mi*16 + lrow) * 64 + co];
      #pragma unroll
      for (int ni = 0; ni < 4; ++ni)
        fb[ni] = *(const bf16x8*)&Bs[(wc*64 + ni*16 + lrow) * 64 + co];
      #pragma unroll
      for (int mi = 0; mi < 4; ++mi)
        #pragma unroll
        for (int ni = 0; ni < 4; ++ni)
          acc[mi][ni] = __builtin_amdgcn_mfma_f32_16x16x32_bf16(
              fa[mi], fb[ni], acc[mi][ni], 0, 0, 0);
    }
  }
  if (wc == 0){                       // cols 0..63 only (64..127 are zero pad)
    float* pz = part + (size_t)kz * NN * 64;
    #pragma unroll
    for (int mi = 0; mi < 4; ++mi){
      #pragma unroll
      for (int ni = 0; ni < 4; ++ni){
        int gn = ni*16 + lrow;
        #pragma unroll
        for (int j = 0; j < 4; ++j){
          int gm = bm + wr*64 + mi*16 + (lane >> 4) * 4 + j;
          if (gm < NN)
            pz[(size_t)gm * 64 + gn] = acc[mi][ni][j];
        }
      }
    }
  }
}

// ---------------------------------------------------------------------------
// split-K flash attention, stage 1. Defer-max (T13) in log2 domain.
// TWO queries per thread (q, q+1024); KSPLIT=20 (KCH=100).
// ---------------------------------------------------------------------------
__global__ __launch_bounds__(128) void k_attn_part(const float* __restrict__ qkv,
    float* __restrict__ Pm, float* __restrict__ Pl, float* __restrict__ Pacc)
{
  __shared__ float Ks[KCH][DHD];
  __shared__ float Vs[KCH][DHD];
  const int q1 = blockIdx.x * 128 + threadIdx.x;   // 0..1023
  const int q2 = q1 + 1024;                        // 1024..2047
  const int bh = blockIdx.y;
  const int b  = bh >> 2, h = bh & 3;
  const int ks = blockIdx.z;
  const bool v2 = q2 < SEQ;
  const float SC = 0.25f * 1.4426950408889634f;    // scale * log2(e)
  float qv1[DHD], qv2[DHD];
  {
    const float4* qr = (const float4*)(qkv + ((size_t)(b*SEQ + q1))*192 + h*DHD);
    #pragma unroll
    for (int j = 0; j < 4; ++j){
      float4 t = qr[j];
      qv1[j*4+0] = t.x; qv1[j*4+1] = t.y; qv1[j*4+2] = t.z; qv1[j*4+3] = t.w;
    }
  }
  if (v2){
    const float4* qr = (const float4*)(qkv + ((size_t)(b*SEQ + q2))*192 + h*DHD);
    #pragma unroll
    for (int j = 0; j < 4; ++j){
      float4 t = qr[j];
      qv2[j*4+0] = t.x; qv2[j*4+1] = t.y; qv2[j*4+2] = t.z; qv2[j*4+3] = t.w;
    }
  } else {
    #pragma unroll
    for (int j = 0; j < DHD; ++j) qv2[j] = 0.f;
  }
  const int kbeg = ks * KCH;
  for (int el = threadIdx.x; el < KCH * 4; el += 128){
    int r = el >> 2, d4 = el & 3;
    const float4* base = (const float4*)(qkv + ((size_t)(b*SEQ + kbeg + r))*192 + h*DHD);
    ((float4*)Ks[r])[d4] = base[16 + d4];      // +64 floats  = K block
    ((float4*)Vs[r])[d4] = base[32 + d4];      // +128 floats = V block
  }
  __syncthreads();
  float m1 = -1e30f, l1 = 0.f, a1[DHD] = {};
  float m2 = -1e30f, l2 = 0.f, a2[DHD] = {};
  for (int r = 0; r < KCH; ++r){
    float s1 = 0.f, s2 = 0.f;
    #pragma unroll
    for (int d = 0; d < DHD; ++d){
      float kd = Ks[r][d];
      s1 = fmaf(qv1[d], kd, s1);
      s2 = fmaf(qv2[d], kd, s2);
    }
    s1 *= SC; s2 *= SC;
    if (__any((s1 > m1 + 8.f) || (s2 > m2 + 8.f))){
      float mn1 = fmaxf(m1, s1), mn2 = fmaxf(m2, s2);
      float c1 = exp2f(m1 - mn1), c2 = exp2f(m2 - mn2);
      l1 *= c1; l2 *= c2;
      #pragma unroll
      for (int d = 0; d < DHD; ++d){ a1[d] *= c1; a2[d] *= c2; }
      m1 = mn1; m2 = mn2;
    }
    float p1 = exp2f(s1 - m1), p2 = exp2f(s2 - m2);
    l1 += p1; l2 += p2;
    #pragma unroll
    for (int d = 0; d < DHD; ++d){
      float vd = Vs[r][d];
      a1[d] = fmaf(p1, vd, a1[d]);
      a2[d] = fmaf(p2, vd, a2[d]);
    }
  }
  {
    size_t qi = ((size_t)bh * SEQ + q1) * KSPLIT + ks;
    Pm[qi] = m1; Pl[qi] = l1;
    #pragma unroll
    for (int d = 0; d < DHD; ++d) Pacc[qi*DHD + d] = a1[d];
  }
  if (v2){
    size_t qi = ((size_t)bh * SEQ + q2) * KSPLIT + ks;
    Pm[qi] = m2; Pl[qi] = l2;
    #pragma unroll
    for (int d = 0; d < DHD; ++d) Pacc[qi*DHD + d] = a2[d];
  }
}

// stage 2: merge KSPLIT partials per query -> o[N][64] (log2 domain)
__global__ void k_attn_comb(const float* __restrict__ Pm, const float* __restrict__ Pl,
                            const float* __restrict__ Pacc, float* __restrict__ o)
{
  int qi = blockIdx.x * blockDim.x + threadIdx.x;
  if (qi >= BATCH * NHTR * SEQ) return;
  float m = -1e30f;
  #pragma unroll
  for (int ks = 0; ks < KSPLIT; ++ks) m = fmaxf(m, Pm[(size_t)qi*KSPLIT + ks]);
  float l = 0.f, acc[DHD] = {};
  #pragma unroll
  for (int ks = 0; ks < KSPLIT; ++ks){
    size_t p = (size_t)qi*KSPLIT + ks;
    float sc = exp2f(Pm[p] - m);
    l += Pl[p] * sc;
    #pragma unroll
    for (int d = 0; d < DHD; ++d) acc[d] = fmaf(Pacc[p*DHD + d], sc, acc[d]);
  }
  int bh = qi / SEQ, q = qi - bh * SEQ;
  int b = bh >> 2, h = bh & 3;
  float inv = 1.f / l;
  #pragma unroll
  for (int d = 0; d < DHD; ++d)
    o[((size_t)(b*SEQ + q))*64 + h*DHD + d] = acc[d] * inv;
}

// ---------------------------------------------------------------------------
// addln that also emits bf16 copy of the output (feeds ff1's MFMA A operand).
// ---------------------------------------------------------------------------
__global__ __launch_bounds__(256) void k_addln(const float* __restrict__ x,
    const float* __restrict__ y, const float* __restrict__ g,
    const float* __restrict__ b, float* __restrict__ out,
    short* __restrict__ hbf)
{
  int row = blockIdx.x * 4 + (threadIdx.x >> 6);
  int lane = threadIdx.x & 63;
  if (row >= NN) return;
  float v = x[(size_t)row*64 + lane] + y[(size_t)row*64 + lane];
  float s1 = v, s2 = v * v;
  #pragma unroll
  for (int o = 32; o; o >>= 1){ s1 += __shfl_xor(s1, o); s2 += __shfl_xor(s2, o); }
  float mean = s1 * (1.f/64.f);
  float var  = s2 * (1.f/64.f) - mean * mean;
  float r = rsqrtf(var + 1e-5f);
  float res = (v - mean) * r * g[lane] + b[lane];
  out[(size_t)row*64 + lane] = res;
  hbf[(size_t)row*64 + lane] = (short)f2bf_rn(res);
}

// feats + coord init in one pass (both read xin)
__global__ void k_prep(const float* __restrict__ x, const float* __restrict__ tout,
                       float* __restrict__ feats, float* __restrict__ coord)
{
  int i = blockIdx.x * blockDim.x + threadIdx.x;
  if (i >= NN * 23) return;
  int n = i / 23, c = i - 23*n;
  if (c < 21)
    feats[(size_t)n*21 + c] = (c < 5) ? x[(size_t)n*7 + 2 + c] : tout[(size_t)n*16 + c - 5];
  else
    coord[(size_t)n*2 + (c - 21)] = x[(size_t)n*7 + (c - 21)];
}

// zero hbf pad rows once
__global__ void k_zpad(short* __restrict__ hbf)
{
  int i = blockIdx.x * blockDim.x + threadIdx.x;
  if (i >= (MPAD - NN) * 64) return;
  hbf[(size_t)NN*64 + i] = 0;
}

// ---------------------------------------------------------------------------
// CSR build (by dst). dst for e>=NEDGE is the self-loop e-NEDGE.
// ---------------------------------------------------------------------------
__global__ void k_count(const int* __restrict__ dst, int* __restrict__ cnt)
{
  int e = blockIdx.x * blockDim.x + threadIdx.x;
  if (e >= ELOOP) return;
  int d = (e < NEDGE) ? dst[e] : e - NEDGE;
  atomicAdd(&cnt[d], 1);
}

__global__ __launch_bounds__(1024) void k_scan(const int* __restrict__ cnt,
                                               int* __restrict__ ptr)
{
  __shared__ int part[1024];
  int tid = threadIdx.x;
  const int per = 8;
  int loc[per]; int s = 0;
  int base = tid * per;
  #pragma unroll
  for (int i = 0; i < per; ++i){
    int v = (base + i < NN) ? cnt[base + i] : 0;
    loc[i] = s; s += v;
  }
  part[tid] = s;
  __syncthreads();
  for (int off = 1; off < 1024; off <<= 1){
    int v = 0;
    if (tid >= off) v = part[tid - off];
    __syncthreads();
    if (tid >= off) part[tid] += v;
    __syncthreads();
  }
  int pre = tid ? part[tid - 1] : 0;
  #pragma unroll
  for (int i = 0; i < per; ++i)
    if (base + i < NN) ptr[base + i] = pre + loc[i];
  if (tid == 1023) ptr[NN] = part[1023];
}

__global__ void k_fill(const int* __restrict__ dst, const int* __restrict__ ptr,
                       int* __restrict__ fil, int* __restrict__ eid)
{
  int e = blockIdx.x * blockDim.x + threadIdx.x;
  if (e >= ELOOP) return;
  int d = (e < NEDGE) ? dst[e] : e - NEDGE;
  int pos = ptr[d] + atomicAdd(&fil[d], 1);
  eid[pos] = e;
}

// ---------------------------------------------------------------------------
// logits2[pos*6+h] over CSR (dst-sorted) positions. One WAVE per edge,
// looping over the 6 heads. Combined xc (stride GOUT2): xl = +0, xr = +GOUT.
// XCD swizzle (10000 = 8 * 1250).
// ---------------------------------------------------------------------------
__global__ __launch_bounds__(256) void k_logits(const unsigned short* __restrict__ xc,
    const int* __restrict__ src_a, const int* __restrict__ dst_a,
    const int* __restrict__ eid, const float* __restrict__ att,
    float* __restrict__ logits2)
{
  int bid = blockIdx.x;                         // 10000 = 8 * 1250
  int wgs = (bid & 7) * 1250 + (bid >> 3);      // bijective XCD chunking
  int pos = wgs * 4 + (threadIdx.x >> 6);
  if (pos >= ELOOP) return;
  int lane = threadIdx.x & 63;
  int e = eid[pos];
  int s = (e < NEDGE) ? src_a[e] : e - NEDGE;
  int d = (e < NEDGE) ? dst_a[e] : e - NEDGE;
  const uint4* pl = (const uint4*)(xc + (size_t)s * GOUT2);
  const uint4* pr = (const uint4*)(xc + (size_t)d * GOUT2 + GOUT);
  const float4* pa = (const float4*)att;
  #pragma unroll 2
  for (int h = 0; h < NHEADS; ++h){
    uint4 ua = pl[h*64 + lane];
    uint4 ub = pr[h*64 + lane];
    float4 w0 = pa[h*128 + lane*2], w1 = pa[h*128 + lane*2 + 1];
    float acc = 0.f;
    auto pair = [&](unsigned a, unsigned b, float wl, float wh){
      float vl = __uint_as_float(a << 16)        + __uint_as_float(b << 16);
      float vh = __uint_as_float(a & 0xffff0000u)+ __uint_as_float(b & 0xffff0000u);
      vl = vl > 0.f ? vl : 0.2f * vl;
      vh = vh > 0.f ? vh : 0.2f * vh;
      acc = fmaf(vl, wl, acc);
      acc = fmaf(vh, wh, acc);
    };
    pair(ua.x, ub.x, w0.x, w0.y);
    pair(ua.y, ub.y, w0.z, w0.w);
    pair(ua.z, ub.z, w1.x, w1.y);
    pair(ua.w, ub.w, w1.z, w1.w);
    #pragma unroll
    for (int o2 = 32; o2; o2 >>= 1) acc += __shfl_xor(acc, o2);
    if (lane == 0) logits2[pos*NHEADS + h] = acc;
  }
}

// ---------------------------------------------------------------------------
// hidden[n,c] = selu(mean_h sum a[e,h]*xl[src,h,c] + gbias[c]); abf refresh.
// Per-head max/inv-sum computed in-block (fused k_stats, same serial order).
// ---------------------------------------------------------------------------
__global__ __launch_bounds__(256) void k_agg(const unsigned short* __restrict__ xc,
    const float* __restrict__ logits2, const int* __restrict__ ptr,
    const int* __restrict__ eid, const int* __restrict__ src_a,
    const float* __restrict__ gbias, float* __restrict__ hidden,
    short* __restrict__ abf)
{
  const int n = blockIdx.x;
  const int tid = threadIdx.x;
  __shared__ float a_sh[64 * NHEADS];
  __shared__ int src_sh[64];
  __shared__ float mx_sh[NHEADS], inv_sh[NHEADS];
  const int s0 = ptr[n];
  const int deg = ptr[n + 1] - s0;
  if (tid < NHEADS){
    float m = -1e30f;
    for (int t = 0; t < deg; ++t)
      m = fmaxf(m, logits2[(size_t)(s0 + t)*NHEADS + tid]);
    float s = 0.f;
    for (int t = 0; t < deg; ++t)
      s += __expf(logits2[(size_t)(s0 + t)*NHEADS + tid] - m);
    mx_sh[tid] = m; inv_sh[tid] = 1.f / s;
  }
  __syncthreads();
  float acc[12] = {};
  for (int base = 0; base < deg; base += 64){
    int cnt = min(64, deg - base);
    __syncthreads();
    for (int t = tid; t < cnt * NHEADS; t += 256){
      int ei = t / NHEADS, h = t - NHEADS * ei;
      a_sh[t] = __expf(logits2[(size_t)(s0 + base + ei)*NHEADS + h] - mx_sh[h])
                * inv_sh[h];
      if (h == 0){
        int e = eid[s0 + base + ei];
        src_sh[ei] = (e < NEDGE) ? src_a[e] : e - NEDGE;
      }
    }
    __syncthreads();
    for (int i2 = 0; i2 < cnt; ++i2){
      const unsigned* row = (const unsigned*)(xc + (size_t)src_sh[i2] * GOUT2);
      #pragma unroll
      for (int k = 0; k < NHEADS; ++k){
        unsigned u = row[tid + (k << 8)];
        float wgt = a_sh[i2*NHEADS + k];
        acc[2*k]   = fmaf(__uint_as_float(u << 16),         wgt, acc[2*k]);
        acc[2*k+1] = fmaf(__uint_as_float(u & 0xffff0000u), wgt, acc[2*k+1]);
      }
    }
  }
  float m0 = (acc[0]+acc[2]+acc[4]+acc[6]+acc[8]+acc[10]) * (1.f/6.f);
  float m1 = (acc[1]+acc[3]+acc[5]+acc[7]+acc[9]+acc[11]) * (1.f/6.f);
  float2 out;
  out.x = selu_f(m0 + gbias[2*tid]);
  out.y = selu_f(m1 + gbias[2*tid + 1]);
  *(float2*)&hidden[(size_t)n*HIDD + 2*tid] = out;
  unsigned short h0 = f2bf_rn(out.x), h1 = f2bf_rn(out.y);
  *(unsigned*)&abf[(size_t)n*K2 + 2 + 2*tid] = (unsigned)h0 | ((unsigned)h1 << 16);
}

// ---------------------------------------------------------------------------
extern "C" void kernel_launch(void* const* d_in, const int* in_sizes, int n_in,
                              void* d_out, int out_size, void* d_ws, size_t ws_size,
                              hipStream_t stream)
{
  const float* mesh     = (const float*)d_in[1];
  const float* xin      = (const float*)d_in[2];
  const int*   ei       = (const int*)d_in[3];
  const float* embed_w  = (const float*)d_in[4];
  const float* embed_b  = (const float*)d_in[5];
  const float* in_proj_w= (const float*)d_in[6];
  const float* in_proj_b= (const float*)d_in[7];
  const float* out_proj_w=(const float*)d_in[8];
  const float* out_proj_b=(const float*)d_in[9];
  const float* ln1_g    = (const float*)d_in[10];
  const float* ln1_b    = (const float*)d_in[11];
  const float* ln2_g    = (const float*)d_in[12];
  const float* ln2_b    = (const float*)d_in[13];
  const float* ff1_w    = (const float*)d_in[14];
  const float* ff1_b    = (const float*)d_in[15];
  const float* ff2_w    = (const float*)d_in[16];
  const float* ff2_b    = (const float*)d_in[17];
  const float* tout_w   = (const float*)d_in[18];
  const float* tout_b   = (const float*)d_in[19];
  const float* lin_w    = (const float*)d_in[20];
  const float* lin_b    = (const float*)d_in[21];
  const float* gat_wl   = (const float*)d_in[22];
  const float* gat_bl   = (const float*)d_in[23];
  const float* gat_wr   = (const float*)d_in[24];
  const float* gat_br   = (const float*)d_in[25];
  const float* gat_att  = (const float*)d_in[26];
  const float* gat_bias = (const float*)d_in[27];
  const float* coord1_w = (const float*)d_in[28];
  const float* coord1_b = (const float*)d_in[29];
  const float* coord2_w = (const float*)d_in[30];
  const float* coord2_b = (const float*)d_in[31];

  const int* esrc = ei;
  const int* edst = ei + NEDGE;

  char* ws = (char*)d_ws;
  size_t off = 0;
  auto alloc = [&](size_t nbytes){
    size_t o = off; off += (nbytes + 255) & ~(size_t)255; return o;
  };
  float* hidden = (float*)(ws + alloc((size_t)NN * HIDD * 4));
  float* coord  = (float*)(ws + alloc((size_t)NN * 2 * 4));
  unsigned short* xc = (unsigned short*)(ws + alloc((size_t)NN * GOUT2 * 2));  // 93.75 MiB
  float* logits = (float*)(ws + alloc((size_t)ELOOP * NHEADS * 4));
  int*   ptr    = (int*)(ws + alloc((size_t)(NN + 1) * 4));
  int*   eid    = (int*)(ws + alloc((size_t)ELOOP * 4));
  int*   cnt    = (int*)(ws + alloc((size_t)NN * 4));
  int*   fil    = (int*)(ws + alloc((size_t)NN * 4));
  short* abf    = (short*)(ws + alloc((size_t)MPAD * K2 * 2));
  short* wlbf   = (short*)(ws + alloc((size_t)GOUT * K1 * 2));   // contiguous:
  short* wrbf   = (short*)(ws + alloc((size_t)GOUT * K1 * 2));   // wrbf = wlbf + GOUT*K1
  short* wcb    = (short*)(ws + alloc((size_t)256 * K1 * 2));    // coord1 bf16
  short* w1b    = (short*)(ws + alloc((size_t)FFD * 64 * 2));    // ff1 bf16
  short* w2b    = (short*)(ws + alloc((size_t)128 * FFD * 2));   // ff2 bf16 (padded)
  short* hbf    = (short*)(ws + alloc((size_t)MPAD * 64 * 2));   // h bf16
  float* c1     = (float*)(ws + alloc((size_t)NN * 256 * 4));    // 7.8 MiB
  float* Wp     = (float*)(ws + alloc((size_t)192 * 4 * 4));
  float* bp     = (float*)(ws + alloc((size_t)192 * 4));

  // Transformer-phase temporaries ALIASED inside xc (93.75 MiB).
  char* arena = (char*)xc;
  float* h       = (float*)(arena + ((size_t)0  << 20));  // 0-2     (live to ln2)
  float* o       = (float*)(arena + ((size_t)2  << 20));  // 2-4
  float* tmp     = (float*)(arena + ((size_t)4  << 20));  // 4-6
  float* feats   = (float*)(arena + ((size_t)6  << 20));  // 6-6.7
  float* toutb   = (float*)(arena + ((size_t)7  << 20));  // 7-7.6
  float* qkv     = (float*)(arena + ((size_t)8  << 20));  // 8-14.2  (dead after attn)
  float* Pm      = (float*)(arena + ((size_t)15 << 20));  // 15-17.5 (KSPLIT=20)
  float* Pl      = (float*)(arena + ((size_t)18 << 20));  // 18-20.5
  float* Pacc    = (float*)(arena + ((size_t)21 << 20));  // 21-62   (dead after comb)
  unsigned short* ffb = (unsigned short*)(arena + ((size_t)28 << 20)); // 28-61 (Pacc dead)
  float* part_f2 = (float*)(arena + ((size_t)62 << 20));  // 62-70.2 (free)

  // ---- once: weight conversions + CSR ----
  k_wfuse<<<1, 192, 0, stream>>>(in_proj_w, in_proj_b, embed_w, embed_b, Wp, bp);
  k_cvt_w1<<<CDIV(FFD*64, 256), 256, 0, stream>>>(ff1_w, w1b);
  k_cvt_w2<<<CDIV(128*FFD, 256), 256, 0, stream>>>(ff2_w, w2b);
  k_zpad<<<CDIV((MPAD-NN)*64, 256), 256, 0, stream>>>(hbf);
  hipMemsetAsync(cnt, 0, (size_t)NN * 4, stream);
  hipMemsetAsync(fil, 0, (size_t)NN * 4, stream);
  k_count<<<CDIV(ELOOP, 256), 256, 0, stream>>>(edst, cnt);
  k_scan<<<1, 1024, 0, stream>>>(cnt, ptr);
  k_fill<<<CDIV(ELOOP, 256), 256, 0, stream>>>(edst, ptr, fil, eid);
  k_cvt_w<<<CDIV(GOUT*K1, 256), 256, 0, stream>>>(gat_wl, wlbf);
  k_cvt_w<<<CDIV(GOUT*K1, 256), 256, 0, stream>>>(gat_wr, wrbf);
  k_cvt_wc<<<CDIV(256*K1, 256), 256, 0, stream>>>(coord1_w, wcb);

  // ---- transformer ----
  k_embqkv<<<NN, 256, 0, stream>>>(mesh, embed_w, embed_b, Wp, bp, h, qkv);
  k_attn_part<<<dim3(CDIV(SEQ,256), BATCH*NHTR, KSPLIT), 128, 0, stream>>>(qkv, Pm, Pl, Pacc);
  k_attn_comb<<<CDIV(BATCH*NHTR*SEQ, 256), 256, 0, stream>>>(Pm, Pl, Pacc, o);
  k_gemm<0><<<dim3(1, CDIV(NN,64)), 256, 0, stream>>>(o, out_proj_w, out_proj_b, tmp, NN, 64, 64);
  k_addln<<<CDIV(NN,4), 256, 0, stream>>>(h, tmp, ln1_g, ln1_b, h, hbf);
  k_ff1_mfma<<<dim3(16, 63), 256, 0, stream>>>(hbf, w1b, ff1_b, ffb);
  k_ff2_mfma<<<dim3(1, 63, 4), 256, 0, stream>>>(ffb, w2b, part_f2);
  k_addln4<<<CDIV(NN,4), 256, 0, stream>>>(h, part_f2, ff2_b, ln2_g, ln2_b, h);
  k_gemm<0><<<dim3(1, CDIV(NN,64)), 256, 0, stream>>>(h, tout_w, tout_b, toutb, NN, TOUTD, DTR);
  k_prep<<<CDIV(NN*23, 256), 256, 0, stream>>>(xin, toutb, feats, coord);
  k_gemm<2><<<dim3(CDIV(HIDD,64), CDIV(NN,64)), 256, 0, stream>>>(feats, lin_w, lin_b, hidden, NN, HIDD, 21);
  k_cvt_a<<<CDIV(MPAD*K1, 256), 256, 0, stream>>>(coord, hidden, abf);  // once

  // ---- GAT loops (abf refreshed in-place by k_agg / k_coord2) ----
  for (int it = 0; it < 3; ++it){
    k_gat_mfma<<<dim3(48, 63), 256, 0, stream>>>(abf, wlbf, gat_bl, gat_br, xc);
    k_logits<<<ELOOP/4, 256, 0, stream>>>(xc, esrc, edst, eid, gat_att, logits);
    k_agg<<<NN, 256, 0, stream>>>(xc, logits, ptr, eid, esrc, gat_bias, hidden, abf);
    k_c1_mfma<<<dim3(2, 63), 256, 0, stream>>>(abf, wcb, coord1_b, c1);
    float* cdst = (it == 2) ? (float*)d_out : coord;
    k_coord2<<<NN, 256, 0, stream>>>(c1, coord2_w, coord2_b, cdst, abf);
  }
}